// Round 1
// baseline (11461.855 us; speedup 1.0000x reference)
//
#include <hip/hip_runtime.h>
#include <math.h>

// ---------------------------------------------------------------------------
// TransformerContinuous: B=8, Lx=512, n_w=384, S=896, D=1024, H=16, hd=64,
// NL=4, FF=4096, HAM=144.  All fp32 (round 1: correctness-first).
// ---------------------------------------------------------------------------

#define B_      8
#define LX_     512
#define NW_     384
#define S_      896
#define D_      1024
#define H_      16
#define HD_     64
#define FF_     4096
#define HAM_    144

#define RMS_SCALE 0.9999500037496876f           // 1/sqrt(1.0001)
#define PE_C     (-6.907755278982137f / 1024.0f) // -ln(1000)/D

static __device__ __forceinline__ float nan0(float v) { return (v != v) ? 0.0f : v; }

// ---------------- embed x: rows (b,i) of x -> tgt rows 0..511 ----------------
__global__ __launch_bounds__(256) void embed_x_kernel(
        const float* __restrict__ x, const float* __restrict__ W_nail,
        const float* __restrict__ b_nail, float* __restrict__ tgt,
        int* __restrict__ xmask) {
    int row = blockIdx.x;              // b*512 + i
    int b = row >> 9, i = row & 511;
    const float* xr = x + (long)row * 64;
    __shared__ float xn[64];
    __shared__ float t_s;
    int tid = threadIdx.x;
    if (tid < 64) {
        float vv = xr[tid];
        float v0 = nan0(vv);
        xn[tid] = fminf(fmaxf(v0 * RMS_SCALE, -5.0f), 5.0f);
        if (tid == 0) { t_s = v0; xmask[row] = (vv != vv) ? 1 : 0; }
    }
    __syncthreads();
    float t = t_s;
    int d0 = tid * 4;
    float acc[4];
#pragma unroll
    for (int j = 0; j < 4; ++j) acc[j] = b_nail[d0 + j];
    const float* w0 = W_nail + (long)d0 * 63;
    for (int k = 0; k < 63; ++k) {
        float xv = xn[k + 1];
#pragma unroll
        for (int j = 0; j < 4; ++j) acc[j] += xv * w0[j * 63 + k];
    }
    float out[4];
#pragma unroll
    for (int j = 0; j < 4; ++j) {
        int d = d0 + j;
        float div = expf((float)(d >> 1) * PE_C);
        float ang = t * div;
        out[j] = acc[j] + ((d & 1) ? cosf(ang) : sinf(ang));
    }
    *(float4*)&tgt[((long)b * S_ + i) * D_ + d0] =
        make_float4(out[0], out[1], out[2], out[3]);
}

// ---------------- embed w: rows (b,j) of w -> tgt rows 512..895 ----------------
__global__ __launch_bounds__(256) void embed_w_kernel(
        const float* __restrict__ w, const float* __restrict__ W_cond,
        const float* __restrict__ b_cond, float* __restrict__ tgt) {
    int row = blockIdx.x;              // b*384 + j
    int b = row / NW_, j = row % NW_;
    const float* wr = w + (long)row * 6;
    float wn[6];
#pragma unroll
    for (int k = 0; k < 6; ++k)
        wn[k] = fminf(fmaxf(nan0(wr[k]) * RMS_SCALE, -5.0f), 5.0f);
    int tid = threadIdx.x;
    int d0 = tid * 4;
    float pos = (float)(LX_ + j);
    float out[4];
#pragma unroll
    for (int jj = 0; jj < 4; ++jj) {
        int d = d0 + jj;
        float acc = b_cond[d];
        const float* wc = W_cond + (long)d * 6;
#pragma unroll
        for (int k = 0; k < 6; ++k) acc += wn[k] * wc[k];
        float div = expf((float)(d >> 1) * PE_C);
        float ang = pos * div;
        out[jj] = acc + ((d & 1) ? cosf(ang) : sinf(ang));
    }
    *(float4*)&tgt[((long)b * S_ + LX_ + j) * D_ + d0] =
        make_float4(out[0], out[1], out[2], out[3]);
}

// ---------------- tiled NT GEMM: C[M,N] = A[M,K] @ W[N,K]^T + bias -----------
// MODE 0: plain+bias   MODE 1: bias+exact GELU   MODE 2: bias + QKV split
#define GM_BM 64
#define GM_BN 64
#define GM_BK 16

template <int MODE>
__global__ __launch_bounds__(256) void gemm_nt(
        const float* __restrict__ A, const float* __restrict__ W,
        const float* __restrict__ bias, float* __restrict__ C,
        float* __restrict__ Cq, float* __restrict__ Ck, float* __restrict__ Cv,
        int M, int N, int K) {
    __shared__ float As[GM_BK][GM_BM + 4];
    __shared__ float Bs[GM_BK][GM_BN + 4];
    int tid = threadIdx.x;
    int tx = tid & 15, ty = tid >> 4;
    int m0 = blockIdx.y * GM_BM, n0 = blockIdx.x * GM_BN;
    int lr = tid >> 2;                 // 0..63
    int lk = (tid & 3) * 4;            // 0,4,8,12
    const float* Aptr = A + (long)(m0 + lr) * K + lk;
    const float* Wptr = W + (long)(n0 + lr) * K + lk;
    float c[4][4] = {};
    for (int k0 = 0; k0 < K; k0 += GM_BK) {
        float4 av = *(const float4*)(Aptr + k0);
        float4 bv = *(const float4*)(Wptr + k0);
        As[lk + 0][lr] = av.x; As[lk + 1][lr] = av.y;
        As[lk + 2][lr] = av.z; As[lk + 3][lr] = av.w;
        Bs[lk + 0][lr] = bv.x; Bs[lk + 1][lr] = bv.y;
        Bs[lk + 2][lr] = bv.z; Bs[lk + 3][lr] = bv.w;
        __syncthreads();
#pragma unroll
        for (int k = 0; k < GM_BK; ++k) {
            float4 a = *(const float4*)&As[k][ty * 4];
            float4 bb = *(const float4*)&Bs[k][tx * 4];
            float a4[4] = {a.x, a.y, a.z, a.w};
            float b4[4] = {bb.x, bb.y, bb.z, bb.w};
#pragma unroll
            for (int i = 0; i < 4; ++i)
#pragma unroll
                for (int j = 0; j < 4; ++j) c[i][j] += a4[i] * b4[j];
        }
        __syncthreads();
    }
    float4 bz = *(const float4*)&bias[n0 + tx * 4];
    float b4[4] = {bz.x, bz.y, bz.z, bz.w};
#pragma unroll
    for (int i = 0; i < 4; ++i) {
        int m = m0 + ty * 4 + i;
        float out[4];
#pragma unroll
        for (int j = 0; j < 4; ++j) {
            float v = c[i][j] + b4[j];
            if (MODE == 1) v = 0.5f * v * (1.0f + erff(v * 0.7071067811865476f));
            out[j] = v;
        }
        float4 o4 = make_float4(out[0], out[1], out[2], out[3]);
        if (MODE == 2) {
            int which = n0 >> 10;            // 0=q 1=k 2=v (tile is 64-aligned)
            int h = (n0 & 1023) >> 6;
            int bb2 = m / S_, s = m % S_;
            float* dst = (which == 0) ? Cq : (which == 1) ? Ck : Cv;
            *(float4*)&dst[(((long)bb2 * H_ + h) * S_ + s) * HD_ + tx * 4] = o4;
        } else {
            *(float4*)&C[(long)m * N + n0 + tx * 4] = o4;
        }
    }
}

// ---------------- fused flash-style attention (fp32) ------------------------
// q,k,v: (B,H,S,64).  ctx out: (B,S,D) with D index = h*64+e.
__global__ __launch_bounds__(256) void attn_kernel(
        const float* __restrict__ q, const float* __restrict__ k,
        const float* __restrict__ v, const int* __restrict__ xmask,
        float* __restrict__ ctx) {
    __shared__ float Qs[32][68];
    __shared__ float Kt[64][68];   // transposed: Kt[d][kk]
    __shared__ float Vs[64][68];   // Vs[kk][d]
    __shared__ float Ps[32][68];
    int tid = threadIdx.x;
    int blk = blockIdx.x;
    int qt = blk % 28;
    int bh = blk / 28;
    int b = bh >> 4;
    int q0 = qt * 32;
    long base = (long)bh * S_ * HD_;
    {   // load Q tile
        int r = tid >> 3, dc = (tid & 7) * 8;
        const float* src = q + base + (long)(q0 + r) * HD_ + dc;
        *(float4*)&Qs[r][dc]     = *(const float4*)src;
        *(float4*)&Qs[r][dc + 4] = *(const float4*)(src + 4);
    }
    int r = tid >> 3, c = tid & 7;
    int qg = q0 + r;
    float m = -INFINITY, l = 0.0f;
    float o[8] = {};
    int kend = (q0 >= LX_) ? ((((q0 + 31) >> 6) + 1) << 6) : LX_;
    for (int k0 = 0; k0 < kend; k0 += 64) {
        {   // load K (transposed) + V tiles
            int kr = tid >> 2;
            int dq = (tid & 3) * 16;
            const float* ks = k + base + (long)(k0 + kr) * HD_ + dq;
            const float* vs = v + base + (long)(k0 + kr) * HD_ + dq;
#pragma unroll
            for (int i = 0; i < 4; ++i) {
                float4 kv = *(const float4*)(ks + i * 4);
                Kt[dq + i * 4 + 0][kr] = kv.x;
                Kt[dq + i * 4 + 1][kr] = kv.y;
                Kt[dq + i * 4 + 2][kr] = kv.z;
                Kt[dq + i * 4 + 3][kr] = kv.w;
                *(float4*)&Vs[kr][dq + i * 4] = *(const float4*)(vs + i * 4);
            }
        }
        __syncthreads();
        float s[8] = {};
#pragma unroll 8
        for (int d = 0; d < 64; ++d) {
            float qv = Qs[r][d];
            float4 k1 = *(const float4*)&Kt[d][c * 8];
            float4 k2 = *(const float4*)&Kt[d][c * 8 + 4];
            s[0] += qv * k1.x; s[1] += qv * k1.y; s[2] += qv * k1.z; s[3] += qv * k1.w;
            s[4] += qv * k2.x; s[5] += qv * k2.y; s[6] += qv * k2.z; s[7] += qv * k2.w;
        }
        float tm = -INFINITY;
#pragma unroll
        for (int j = 0; j < 8; ++j) {
            int kj = k0 + c * 8 + j;
            bool masked = (kj < LX_) ? (xmask[(b << 9) + kj] != 0) : (kj > qg);
            s[j] = masked ? -INFINITY : s[j] * 0.125f;
            tm = fmaxf(tm, s[j]);
        }
#pragma unroll
        for (int off = 1; off < 8; off <<= 1) tm = fmaxf(tm, __shfl_xor(tm, off, 64));
        float newm = fmaxf(m, tm);
        float alpha = (newm == -INFINITY) ? 1.0f : __expf(m - newm);
        float p[8]; float rsum = 0.0f;
#pragma unroll
        for (int j = 0; j < 8; ++j) {
            p[j] = (s[j] == -INFINITY) ? 0.0f : __expf(s[j] - newm);
            rsum += p[j];
        }
#pragma unroll
        for (int off = 1; off < 8; off <<= 1) rsum += __shfl_xor(rsum, off, 64);
        l = l * alpha + rsum;
        m = newm;
#pragma unroll
        for (int j = 0; j < 8; ++j) o[j] *= alpha;
        *(float4*)&Ps[r][c * 8]     = make_float4(p[0], p[1], p[2], p[3]);
        *(float4*)&Ps[r][c * 8 + 4] = make_float4(p[4], p[5], p[6], p[7]);
        __syncthreads();
#pragma unroll 8
        for (int kk = 0; kk < 64; ++kk) {
            float pv = Ps[r][kk];
            float4 v1 = *(const float4*)&Vs[kk][c * 8];
            float4 v2 = *(const float4*)&Vs[kk][c * 8 + 4];
            o[0] += pv * v1.x; o[1] += pv * v1.y; o[2] += pv * v1.z; o[3] += pv * v1.w;
            o[4] += pv * v2.x; o[5] += pv * v2.y; o[6] += pv * v2.z; o[7] += pv * v2.w;
        }
        __syncthreads();
    }
    float inv = (l > 0.0f) ? 1.0f / l : 0.0f;
    int h = bh & 15;
    long ob = ((long)b * S_ + qg) * D_ + h * HD_ + c * 8;
    *(float4*)&ctx[ob]     = make_float4(o[0]*inv, o[1]*inv, o[2]*inv, o[3]*inv);
    *(float4*)&ctx[ob + 4] = make_float4(o[4]*inv, o[5]*inv, o[6]*inv, o[7]*inv);
}

// ---------------- fused residual add + LayerNorm (in-place on xs) -----------
__global__ __launch_bounds__(256) void add_ln_kernel(
        float* __restrict__ xs, const float* __restrict__ o,
        const float* __restrict__ g, const float* __restrict__ bb) {
    long row = blockIdx.x;
    float* xr = xs + row * D_;
    const float* orr = o + row * D_;
    int tid = threadIdx.x;
    float4 a = *(const float4*)&xr[tid * 4];
    float4 b = *(const float4*)&orr[tid * 4];
    float vv[4] = {a.x + b.x, a.y + b.y, a.z + b.z, a.w + b.w};
    float s = vv[0] + vv[1] + vv[2] + vv[3];
    __shared__ float red[4];
    __shared__ float stat;
#pragma unroll
    for (int off = 32; off; off >>= 1) s += __shfl_down(s, off, 64);
    if ((tid & 63) == 0) red[tid >> 6] = s;
    __syncthreads();
    if (tid == 0) stat = (red[0] + red[1] + red[2] + red[3]) * (1.0f / 1024.0f);
    __syncthreads();
    float mean = stat;
    float d[4];
    float s2 = 0.0f;
#pragma unroll
    for (int j = 0; j < 4; ++j) { d[j] = vv[j] - mean; s2 += d[j] * d[j]; }
    __syncthreads();
#pragma unroll
    for (int off = 32; off; off >>= 1) s2 += __shfl_down(s2, off, 64);
    if ((tid & 63) == 0) red[tid >> 6] = s2;
    __syncthreads();
    if (tid == 0) stat = (red[0] + red[1] + red[2] + red[3]) * (1.0f / 1024.0f);
    __syncthreads();
    float inv = 1.0f / sqrtf(stat + 1e-5f);
    float4 gg = *(const float4*)&g[tid * 4];
    float4 bv = *(const float4*)&bb[tid * 4];
    float g4[4] = {gg.x, gg.y, gg.z, gg.w};
    float b4[4] = {bv.x, bv.y, bv.z, bv.w};
    float out[4];
#pragma unroll
    for (int j = 0; j < 4; ++j) out[j] = d[j] * inv * g4[j] + b4[j];
    *(float4*)&xr[tid * 4] = make_float4(out[0], out[1], out[2], out[3]);
}

// ---------------- head: (8,1024) @ W_ham^T + b_ham -> (8,144) ----------------
__global__ __launch_bounds__(256) void head_kernel(
        const float* __restrict__ tgt, const float* __restrict__ W_ham,
        const float* __restrict__ b_ham, float* __restrict__ out) {
    int b = blockIdx.x;
    int tid = threadIdx.x;
    __shared__ float xr[D_];
    const float* row = tgt + ((long)b * S_ + (S_ - 1)) * D_;
    for (int i = tid; i < D_; i += 256) xr[i] = row[i];
    __syncthreads();
    for (int n = tid; n < HAM_; n += 256) {
        float acc = b_ham[n];
        const float* wr = W_ham + (long)n * D_;
        for (int kk = 0; kk < D_; ++kk) acc += xr[kk] * wr[kk];
        out[b * HAM_ + n] = acc;
    }
}

// ---------------- loss: mean((head_out - (y - w_last))^2) --------------------
__global__ __launch_bounds__(256) void loss_kernel(
        const float* __restrict__ head_out, const float* __restrict__ y,
        const float* __restrict__ w, float* __restrict__ out) {
    int tid = threadIdx.x;
    float acc = 0.0f;
    for (int i = tid; i < B_ * HAM_; i += 256) {
        int b = i / HAM_, r = i % HAM_;
        float w_last = w[((long)b * 16 + 15) * HAM_ + r];   // w[b,15,:,:]
        float resid = y[i] - w_last;
        float dd = head_out[i] - resid;
        acc += dd * dd;
    }
    __shared__ float red[4];
#pragma unroll
    for (int off = 32; off; off >>= 1) acc += __shfl_down(acc, off, 64);
    if ((tid & 63) == 0) red[tid >> 6] = acc;
    __syncthreads();
    if (tid == 0)
        out[0] = (red[0] + red[1] + red[2] + red[3]) * (1.0f / (B_ * HAM_));
}

// ---------------------------------------------------------------------------
extern "C" void kernel_launch(void* const* d_in, const int* in_sizes, int n_in,
                              void* d_out, int out_size, void* d_ws, size_t ws_size,
                              hipStream_t stream) {
    const float* x      = (const float*)d_in[0];
    const float* w      = (const float*)d_in[1];
    const float* y      = (const float*)d_in[2];
    const float* W_nail = (const float*)d_in[3];
    const float* b_nail = (const float*)d_in[4];
    const float* W_cond = (const float*)d_in[5];
    const float* b_cond = (const float*)d_in[6];
    const float* Wqkv   = (const float*)d_in[7];
    const float* bqkv   = (const float*)d_in[8];
    const float* Wo     = (const float*)d_in[9];
    const float* bo     = (const float*)d_in[10];
    const float* ln1_g  = (const float*)d_in[11];
    const float* ln1_b  = (const float*)d_in[12];
    const float* ln2_g  = (const float*)d_in[13];
    const float* ln2_b  = (const float*)d_in[14];
    const float* W1     = (const float*)d_in[15];
    const float* b1     = (const float*)d_in[16];
    const float* W2     = (const float*)d_in[17];
    const float* b2     = (const float*)d_in[18];
    const float* W_ham  = (const float*)d_in[19];
    const float* b_ham  = (const float*)d_in[20];

    float* ws = (float*)d_ws;
    const long SEG = (long)B_ * S_ * D_;      // 7,340,032 floats
    float* tgt = ws;
    float* qb  = ws + SEG;
    float* kb  = ws + 2 * SEG;
    float* vb  = ws + 3 * SEG;
    float* ctx = ws + 4 * SEG;
    float* tmp = ws + 5 * SEG;
    float* ffh = qb;                           // 7168*4096 == 4*SEG, overlays q|k|v|ctx
    int*   xmask    = (int*)(ws + 6 * SEG);
    float* head_out = ws + 6 * SEG + 4096;

    const int M = B_ * S_;                     // 7168

    embed_x_kernel<<<B_ * LX_, 256, 0, stream>>>(x, W_nail, b_nail, tgt, xmask);
    embed_w_kernel<<<B_ * NW_, 256, 0, stream>>>(w, W_cond, b_cond, tgt);

    for (int L = 0; L < 4; ++L) {
        gemm_nt<2><<<dim3(3 * D_ / GM_BN, M / GM_BM), 256, 0, stream>>>(
            tgt, Wqkv + (long)L * 3 * D_ * D_, bqkv + (long)L * 3 * D_,
            nullptr, qb, kb, vb, M, 3 * D_, D_);
        attn_kernel<<<B_ * H_ * (S_ / 32), 256, 0, stream>>>(qb, kb, vb, xmask, ctx);
        gemm_nt<0><<<dim3(D_ / GM_BN, M / GM_BM), 256, 0, stream>>>(
            ctx, Wo + (long)L * D_ * D_, bo + (long)L * D_,
            tmp, nullptr, nullptr, nullptr, M, D_, D_);
        add_ln_kernel<<<M, 256, 0, stream>>>(tgt, tmp, ln1_g + (long)L * D_, ln1_b + (long)L * D_);
        gemm_nt<1><<<dim3(FF_ / GM_BN, M / GM_BM), 256, 0, stream>>>(
            tgt, W1 + (long)L * FF_ * D_, b1 + (long)L * FF_,
            ffh, nullptr, nullptr, nullptr, M, FF_, D_);
        gemm_nt<0><<<dim3(D_ / GM_BN, M / GM_BM), 256, 0, stream>>>(
            ffh, W2 + (long)L * D_ * FF_, b2 + (long)L * D_,
            tmp, nullptr, nullptr, nullptr, M, D_, FF_);
        add_ln_kernel<<<M, 256, 0, stream>>>(tgt, tmp, ln2_g + (long)L * D_, ln2_b + (long)L * D_);
    }

    head_kernel<<<B_, 256, 0, stream>>>(tgt, W_ham, b_ham, head_out);
    loss_kernel<<<1, 256, 0, stream>>>(head_out, y, w, (float*)d_out);
}

// Round 2
// 3521.386 us; speedup vs baseline: 3.2549x; 3.2549x over previous
//
#include <hip/hip_runtime.h>
#include <math.h>

// ---------------------------------------------------------------------------
// TransformerContinuous: B=8, Lx=512, n_w=384, S=896, D=1024, H=16, hd=64,
// NL=4, FF=4096, HAM=144.
// Round 2: big GEMMs -> bf16 MFMA (16x16x32, 128x128 tile, global_load_lds).
// ---------------------------------------------------------------------------

#define B_      8
#define LX_     512
#define NW_     384
#define S_      896
#define D_      1024
#define H_      16
#define HD_     64
#define FF_     4096
#define HAM_    144

#define RMS_SCALE 0.9999500037496876f            // 1/sqrt(1.0001)
#define PE_C     (-6.907755278982137f / 1024.0f) // -ln(1000)/D

typedef __bf16 bf16x4 __attribute__((ext_vector_type(4)));
typedef __bf16 bf16x8 __attribute__((ext_vector_type(8)));
typedef float  f32x4  __attribute__((ext_vector_type(4)));

static __device__ __forceinline__ float nan0(float v) { return (v != v) ? 0.0f : v; }

static __device__ __forceinline__ void async_copy16(const __bf16* g, __bf16* l) {
    __builtin_amdgcn_global_load_lds(
        (const __attribute__((address_space(1))) void*)g,
        (__attribute__((address_space(3))) void*)l, 16, 0, 0);
}

// ---------------- fp32 -> bf16 weight conversion (n multiple of 1024) -------
__global__ __launch_bounds__(256) void convert_kernel(
        const float* __restrict__ src, __bf16* __restrict__ dst, int n) {
    int i = (blockIdx.x * 256 + threadIdx.x) * 4;
    float4 v = *(const float4*)&src[i];
    bf16x4 o = {(__bf16)v.x, (__bf16)v.y, (__bf16)v.z, (__bf16)v.w};
    *(bf16x4*)&dst[i] = o;
}

// ---------------- embed x: rows (b,i) of x -> tgt rows 0..511 ----------------
__global__ __launch_bounds__(256) void embed_x_kernel(
        const float* __restrict__ x, const float* __restrict__ W_nail,
        const float* __restrict__ b_nail, float* __restrict__ tgt,
        __bf16* __restrict__ tgt_bf, int* __restrict__ xmask) {
    int row = blockIdx.x;              // b*512 + i
    int b = row >> 9, i = row & 511;
    const float* xr = x + (long)row * 64;
    __shared__ float xn[64];
    __shared__ float t_s;
    int tid = threadIdx.x;
    if (tid < 64) {
        float vv = xr[tid];
        float v0 = nan0(vv);
        xn[tid] = fminf(fmaxf(v0 * RMS_SCALE, -5.0f), 5.0f);
        if (tid == 0) { t_s = v0; xmask[row] = (vv != vv) ? 1 : 0; }
    }
    __syncthreads();
    float t = t_s;
    int d0 = tid * 4;
    float acc[4];
#pragma unroll
    for (int j = 0; j < 4; ++j) acc[j] = b_nail[d0 + j];
    const float* w0 = W_nail + (long)d0 * 63;
    for (int k = 0; k < 63; ++k) {
        float xv = xn[k + 1];
#pragma unroll
        for (int j = 0; j < 4; ++j) acc[j] += xv * w0[j * 63 + k];
    }
    float out[4];
#pragma unroll
    for (int j = 0; j < 4; ++j) {
        int d = d0 + j;
        float div = expf((float)(d >> 1) * PE_C);
        float ang = t * div;
        out[j] = acc[j] + ((d & 1) ? cosf(ang) : sinf(ang));
    }
    long idx = ((long)b * S_ + i) * D_ + d0;
    *(float4*)&tgt[idx] = make_float4(out[0], out[1], out[2], out[3]);
    bf16x4 ob = {(__bf16)out[0], (__bf16)out[1], (__bf16)out[2], (__bf16)out[3]};
    *(bf16x4*)&tgt_bf[idx] = ob;
}

// ---------------- embed w: rows (b,j) of w -> tgt rows 512..895 ----------------
__global__ __launch_bounds__(256) void embed_w_kernel(
        const float* __restrict__ w, const float* __restrict__ W_cond,
        const float* __restrict__ b_cond, float* __restrict__ tgt,
        __bf16* __restrict__ tgt_bf) {
    int row = blockIdx.x;              // b*384 + j
    int b = row / NW_, j = row % NW_;
    const float* wr = w + (long)row * 6;
    float wn[6];
#pragma unroll
    for (int k = 0; k < 6; ++k)
        wn[k] = fminf(fmaxf(nan0(wr[k]) * RMS_SCALE, -5.0f), 5.0f);
    int tid = threadIdx.x;
    int d0 = tid * 4;
    float pos = (float)(LX_ + j);
    float out[4];
#pragma unroll
    for (int jj = 0; jj < 4; ++jj) {
        int d = d0 + jj;
        float acc = b_cond[d];
        const float* wc = W_cond + (long)d * 6;
#pragma unroll
        for (int k = 0; k < 6; ++k) acc += wn[k] * wc[k];
        float div = expf((float)(d >> 1) * PE_C);
        float ang = pos * div;
        out[jj] = acc + ((d & 1) ? cosf(ang) : sinf(ang));
    }
    long idx = ((long)b * S_ + LX_ + j) * D_ + d0;
    *(float4*)&tgt[idx] = make_float4(out[0], out[1], out[2], out[3]);
    bf16x4 ob = {(__bf16)out[0], (__bf16)out[1], (__bf16)out[2], (__bf16)out[3]};
    *(bf16x4*)&tgt_bf[idx] = ob;
}

// ---------------- bf16 MFMA GEMM: C[M,N] = A[M,K] @ W[N,K]^T + bias ---------
// 128x128 tile, BK=32, 4 waves each computing 64x64 via 4x4 16x16x32 MFMAs.
// MODE 0: fp32 out + bias   MODE 1: bf16 out + bias + exact GELU
// MODE 2: fp32 out + bias, split to q/k/v (B,H,S,64)
template <int MODE>
__global__ __launch_bounds__(256) void gemm_mfma(
        const __bf16* __restrict__ A, const __bf16* __restrict__ W,
        const float* __restrict__ bias,
        float* __restrict__ Cf, __bf16* __restrict__ Cb,
        float* __restrict__ Cq, float* __restrict__ Ck, float* __restrict__ Cv,
        int M, int N, int K) {
    __shared__ __bf16 As[128 * 32];
    __shared__ __bf16 Bs[128 * 32];
    int tid = threadIdx.x;
    int wave = tid >> 6, lane = tid & 63;
    int m0 = blockIdx.y * 128, n0 = blockIdx.x * 128;
    int wm = (wave >> 1) * 64, wn = (wave & 1) * 64;

    // staging: each wave stages 2 chunks of A (16 rows x 32 cols) + 2 of B
    int srow = wave * 32 + (lane >> 2);          // rows for chunk pair base
    int scol = (lane & 3) * 8;
    const __bf16* Ag = A + (size_t)(m0 + srow) * K + scol;
    const __bf16* Wg = W + (size_t)(n0 + srow) * K + scol;
    __bf16* Al = &As[wave * 1024];               // 2 chunks x 512 elements
    __bf16* Bl = &Bs[wave * 1024];

    f32x4 acc[4][4];
#pragma unroll
    for (int i = 0; i < 4; ++i)
#pragma unroll
        for (int j = 0; j < 4; ++j) acc[i][j] = 0.0f;

    int frow = lane & 15;                        // fragment row within 16
    int kg = (lane >> 4) * 8;                    // fragment k-offset

    for (int k0 = 0; k0 < K; k0 += 32) {
        async_copy16(Ag + k0, Al);
        async_copy16(Ag + k0 + (size_t)16 * K, Al + 512);
        async_copy16(Wg + k0, Bl);
        async_copy16(Wg + k0 + (size_t)16 * K, Bl + 512);
        __syncthreads();
        bf16x8 a[4], b[4];
#pragma unroll
        for (int mi = 0; mi < 4; ++mi)
            a[mi] = *(const bf16x8*)&As[(wm + mi * 16 + frow) * 32 + kg];
#pragma unroll
        for (int ni = 0; ni < 4; ++ni)
            b[ni] = *(const bf16x8*)&Bs[(wn + ni * 16 + frow) * 32 + kg];
#pragma unroll
        for (int mi = 0; mi < 4; ++mi)
#pragma unroll
            for (int ni = 0; ni < 4; ++ni)
                acc[mi][ni] = __builtin_amdgcn_mfma_f32_16x16x32_bf16(
                    a[mi], b[ni], acc[mi][ni], 0, 0, 0);
        __syncthreads();
    }

    // epilogue: D[row][col], col = lane&15, row = (lane>>4)*4 + r
    int col_l = lane & 15;
    int rquad = (lane >> 4) * 4;
#pragma unroll
    for (int ni = 0; ni < 4; ++ni) {
        int cg = n0 + wn + ni * 16 + col_l;
        float bv = bias[cg];
#pragma unroll
        for (int mi = 0; mi < 4; ++mi) {
#pragma unroll
            for (int r = 0; r < 4; ++r) {
                int rg = m0 + wm + mi * 16 + rquad + r;
                float v = acc[mi][ni][r] + bv;
                if (MODE == 0) {
                    Cf[(size_t)rg * N + cg] = v;
                } else if (MODE == 1) {
                    v = 0.5f * v * (1.0f + erff(v * 0.7071067811865476f));
                    Cb[(size_t)rg * N + cg] = (__bf16)v;
                } else {
                    int which = cg >> 10;        // 0=q 1=k 2=v
                    int h = (cg & 1023) >> 6;
                    int e = cg & 63;
                    int bb = rg / S_, s = rg % S_;
                    float* dst = (which == 0) ? Cq : (which == 1) ? Ck : Cv;
                    dst[(((size_t)bb * H_ + h) * S_ + s) * HD_ + e] = v;
                }
            }
        }
    }
}

// ---------------- fused flash-style attention (fp32, bf16 ctx out) ----------
__global__ __launch_bounds__(256) void attn_kernel(
        const float* __restrict__ q, const float* __restrict__ k,
        const float* __restrict__ v, const int* __restrict__ xmask,
        __bf16* __restrict__ ctx) {
    __shared__ float Qs[32][68];
    __shared__ float Kt[64][68];   // transposed: Kt[d][kk]
    __shared__ float Vs[64][68];   // Vs[kk][d]
    __shared__ float Ps[32][68];
    int tid = threadIdx.x;
    int blk = blockIdx.x;
    int qt = blk % 28;
    int bh = blk / 28;
    int b = bh >> 4;
    int q0 = qt * 32;
    long base = (long)bh * S_ * HD_;
    {   // load Q tile
        int r = tid >> 3, dc = (tid & 7) * 8;
        const float* src = q + base + (long)(q0 + r) * HD_ + dc;
        *(float4*)&Qs[r][dc]     = *(const float4*)src;
        *(float4*)&Qs[r][dc + 4] = *(const float4*)(src + 4);
    }
    int r = tid >> 3, c = tid & 7;
    int qg = q0 + r;
    float m = -INFINITY, l = 0.0f;
    float o[8] = {};
    int kend = (q0 >= LX_) ? ((((q0 + 31) >> 6) + 1) << 6) : LX_;
    for (int k0 = 0; k0 < kend; k0 += 64) {
        {   // load K (transposed) + V tiles
            int kr = tid >> 2;
            int dq = (tid & 3) * 16;
            const float* ks = k + base + (long)(k0 + kr) * HD_ + dq;
            const float* vs = v + base + (long)(k0 + kr) * HD_ + dq;
#pragma unroll
            for (int i = 0; i < 4; ++i) {
                float4 kv = *(const float4*)(ks + i * 4);
                Kt[dq + i * 4 + 0][kr] = kv.x;
                Kt[dq + i * 4 + 1][kr] = kv.y;
                Kt[dq + i * 4 + 2][kr] = kv.z;
                Kt[dq + i * 4 + 3][kr] = kv.w;
                *(float4*)&Vs[kr][dq + i * 4] = *(const float4*)(vs + i * 4);
            }
        }
        __syncthreads();
        float s[8] = {};
#pragma unroll 8
        for (int d = 0; d < 64; ++d) {
            float qv = Qs[r][d];
            float4 k1 = *(const float4*)&Kt[d][c * 8];
            float4 k2 = *(const float4*)&Kt[d][c * 8 + 4];
            s[0] += qv * k1.x; s[1] += qv * k1.y; s[2] += qv * k1.z; s[3] += qv * k1.w;
            s[4] += qv * k2.x; s[5] += qv * k2.y; s[6] += qv * k2.z; s[7] += qv * k2.w;
        }
        float tm = -INFINITY;
#pragma unroll
        for (int j = 0; j < 8; ++j) {
            int kj = k0 + c * 8 + j;
            bool masked = (kj < LX_) ? (xmask[(b << 9) + kj] != 0) : (kj > qg);
            s[j] = masked ? -INFINITY : s[j] * 0.125f;
            tm = fmaxf(tm, s[j]);
        }
#pragma unroll
        for (int off = 1; off < 8; off <<= 1) tm = fmaxf(tm, __shfl_xor(tm, off, 64));
        float newm = fmaxf(m, tm);
        float alpha = (newm == -INFINITY) ? 1.0f : __expf(m - newm);
        float p[8]; float rsum = 0.0f;
#pragma unroll
        for (int j = 0; j < 8; ++j) {
            p[j] = (s[j] == -INFINITY) ? 0.0f : __expf(s[j] - newm);
            rsum += p[j];
        }
#pragma unroll
        for (int off = 1; off < 8; off <<= 1) rsum += __shfl_xor(rsum, off, 64);
        l = l * alpha + rsum;
        m = newm;
#pragma unroll
        for (int j = 0; j < 8; ++j) o[j] *= alpha;
        *(float4*)&Ps[r][c * 8]     = make_float4(p[0], p[1], p[2], p[3]);
        *(float4*)&Ps[r][c * 8 + 4] = make_float4(p[4], p[5], p[6], p[7]);
        __syncthreads();
#pragma unroll 8
        for (int kk = 0; kk < 64; ++kk) {
            float pv = Ps[r][kk];
            float4 v1 = *(const float4*)&Vs[kk][c * 8];
            float4 v2 = *(const float4*)&Vs[kk][c * 8 + 4];
            o[0] += pv * v1.x; o[1] += pv * v1.y; o[2] += pv * v1.z; o[3] += pv * v1.w;
            o[4] += pv * v2.x; o[5] += pv * v2.y; o[6] += pv * v2.z; o[7] += pv * v2.w;
        }
        __syncthreads();
    }
    float inv = (l > 0.0f) ? 1.0f / l : 0.0f;
    int h = bh & 15;
    long ob = ((long)b * S_ + qg) * D_ + h * HD_ + c * 8;
    bf16x8 ov;
#pragma unroll
    for (int j = 0; j < 8; ++j) ov[j] = (__bf16)(o[j] * inv);
    *(bf16x8*)&ctx[ob] = ov;
}

// ---------------- fused residual add + LayerNorm (fp32 + bf16 mirror) -------
__global__ __launch_bounds__(256) void add_ln_kernel(
        float* __restrict__ xs, __bf16* __restrict__ xs_bf,
        const float* __restrict__ o,
        const float* __restrict__ g, const float* __restrict__ bb) {
    long row = blockIdx.x;
    float* xr = xs + row * D_;
    const float* orr = o + row * D_;
    int tid = threadIdx.x;
    float4 a = *(const float4*)&xr[tid * 4];
    float4 b = *(const float4*)&orr[tid * 4];
    float vv[4] = {a.x + b.x, a.y + b.y, a.z + b.z, a.w + b.w};
    float s = vv[0] + vv[1] + vv[2] + vv[3];
    __shared__ float red[4];
    __shared__ float stat;
#pragma unroll
    for (int off = 32; off; off >>= 1) s += __shfl_down(s, off, 64);
    if ((tid & 63) == 0) red[tid >> 6] = s;
    __syncthreads();
    if (tid == 0) stat = (red[0] + red[1] + red[2] + red[3]) * (1.0f / 1024.0f);
    __syncthreads();
    float mean = stat;
    float d[4];
    float s2 = 0.0f;
#pragma unroll
    for (int j = 0; j < 4; ++j) { d[j] = vv[j] - mean; s2 += d[j] * d[j]; }
    __syncthreads();
#pragma unroll
    for (int off = 32; off; off >>= 1) s2 += __shfl_down(s2, off, 64);
    if ((tid & 63) == 0) red[tid >> 6] = s2;
    __syncthreads();
    if (tid == 0) stat = (red[0] + red[1] + red[2] + red[3]) * (1.0f / 1024.0f);
    __syncthreads();
    float inv = 1.0f / sqrtf(stat + 1e-5f);
    float4 gg = *(const float4*)&g[tid * 4];
    float4 bv = *(const float4*)&bb[tid * 4];
    float g4[4] = {gg.x, gg.y, gg.z, gg.w};
    float b4[4] = {bv.x, bv.y, bv.z, bv.w};
    float out[4];
#pragma unroll
    for (int j = 0; j < 4; ++j) out[j] = d[j] * inv * g4[j] + b4[j];
    *(float4*)&xr[tid * 4] = make_float4(out[0], out[1], out[2], out[3]);
    bf16x4 ob = {(__bf16)out[0], (__bf16)out[1], (__bf16)out[2], (__bf16)out[3]};
    *(bf16x4*)&xs_bf[row * D_ + tid * 4] = ob;
}

// ---------------- head: (8,1024) @ W_ham^T + b_ham -> (8,144) ----------------
__global__ __launch_bounds__(256) void head_kernel(
        const float* __restrict__ tgt, const float* __restrict__ W_ham,
        const float* __restrict__ b_ham, float* __restrict__ out) {
    int b = blockIdx.x;
    int tid = threadIdx.x;
    __shared__ float xr[D_];
    const float* row = tgt + ((long)b * S_ + (S_ - 1)) * D_;
    for (int i = tid; i < D_; i += 256) xr[i] = row[i];
    __syncthreads();
    for (int n = tid; n < HAM_; n += 256) {
        float acc = b_ham[n];
        const float* wr = W_ham + (long)n * D_;
        for (int kk = 0; kk < D_; ++kk) acc += xr[kk] * wr[kk];
        out[b * HAM_ + n] = acc;
    }
}

// ---------------- loss: mean((head_out - (y - w_last))^2) --------------------
__global__ __launch_bounds__(256) void loss_kernel(
        const float* __restrict__ head_out, const float* __restrict__ y,
        const float* __restrict__ w, float* __restrict__ out) {
    int tid = threadIdx.x;
    float acc = 0.0f;
    for (int i = tid; i < B_ * HAM_; i += 256) {
        int b = i / HAM_, r = i % HAM_;
        float w_last = w[((long)b * 16 + 15) * HAM_ + r];   // w[b,15,:,:]
        float resid = y[i] - w_last;
        float dd = head_out[i] - resid;
        acc += dd * dd;
    }
    __shared__ float red[4];
#pragma unroll
    for (int off = 32; off; off >>= 1) acc += __shfl_down(acc, off, 64);
    if ((tid & 63) == 0) red[tid >> 6] = acc;
    __syncthreads();
    if (tid == 0)
        out[0] = (red[0] + red[1] + red[2] + red[3]) * (1.0f / (B_ * HAM_));
}

// ---------------------------------------------------------------------------
extern "C" void kernel_launch(void* const* d_in, const int* in_sizes, int n_in,
                              void* d_out, int out_size, void* d_ws, size_t ws_size,
                              hipStream_t stream) {
    const float* x      = (const float*)d_in[0];
    const float* w      = (const float*)d_in[1];
    const float* y      = (const float*)d_in[2];
    const float* W_nail = (const float*)d_in[3];
    const float* b_nail = (const float*)d_in[4];
    const float* W_cond = (const float*)d_in[5];
    const float* b_cond = (const float*)d_in[6];
    const float* Wqkv   = (const float*)d_in[7];
    const float* bqkv   = (const float*)d_in[8];
    const float* Wo     = (const float*)d_in[9];
    const float* bo     = (const float*)d_in[10];
    const float* ln1_g  = (const float*)d_in[11];
    const float* ln1_b  = (const float*)d_in[12];
    const float* ln2_g  = (const float*)d_in[13];
    const float* ln2_b  = (const float*)d_in[14];
    const float* W1     = (const float*)d_in[15];
    const float* b1     = (const float*)d_in[16];
    const float* W2     = (const float*)d_in[17];
    const float* b2     = (const float*)d_in[18];
    const float* W_ham  = (const float*)d_in[19];
    const float* b_ham  = (const float*)d_in[20];

    float* ws = (float*)d_ws;
    const long SEG = (long)B_ * S_ * D_;            // 7,340,032 floats
    float*  tgt    = ws;
    float*  tmp    = ws + SEG;
    float*  qb     = ws + 2 * SEG;
    float*  kb     = ws + 3 * SEG;
    float*  vb     = ws + 4 * SEG;
    __bf16* tgt_bf = (__bf16*)(ws + 5 * SEG);       // SEG bf16
    __bf16* ctx_bf = (__bf16*)(ws + 5 * SEG + SEG / 2);
    __bf16* wbf    = (__bf16*)(ws + 6 * SEG);       // 12,582,912 bf16
    __bf16* ffh_bf = (__bf16*)(ws + 2 * SEG);       // overlays q,k (dead then)
    int*    xmask    = (int*)(ws + 6 * SEG + 6291456 / 1 + 0) ;
    float*  head_out = ws + 6 * SEG + 6291456 + 4096;

    __bf16* wqkv_bf = wbf;
    __bf16* wo_bf   = wbf + 3145728;
    __bf16* w1_bf   = wbf + 4194304;
    __bf16* w2_bf   = wbf + 8388608;

    const int M = B_ * S_;                          // 7168

    embed_x_kernel<<<B_ * LX_, 256, 0, stream>>>(x, W_nail, b_nail, tgt, tgt_bf, xmask);
    embed_w_kernel<<<B_ * NW_, 256, 0, stream>>>(w, W_cond, b_cond, tgt, tgt_bf);

    for (int L = 0; L < 4; ++L) {
        const int NQ = 3 * D_ * D_, NO = D_ * D_, N1 = FF_ * D_, N2 = D_ * FF_;
        convert_kernel<<<NQ / 1024, 256, 0, stream>>>(Wqkv + (size_t)L * NQ, wqkv_bf, NQ);
        convert_kernel<<<NO / 1024, 256, 0, stream>>>(Wo   + (size_t)L * NO, wo_bf,   NO);
        convert_kernel<<<N1 / 1024, 256, 0, stream>>>(W1   + (size_t)L * N1, w1_bf,   N1);
        convert_kernel<<<N2 / 1024, 256, 0, stream>>>(W2   + (size_t)L * N2, w2_bf,   N2);

        gemm_mfma<2><<<dim3(3 * D_ / 128, M / 128), 256, 0, stream>>>(
            tgt_bf, wqkv_bf, bqkv + (size_t)L * 3 * D_,
            nullptr, nullptr, qb, kb, vb, M, 3 * D_, D_);
        attn_kernel<<<B_ * H_ * (S_ / 32), 256, 0, stream>>>(qb, kb, vb, xmask, ctx_bf);
        gemm_mfma<0><<<dim3(D_ / 128, M / 128), 256, 0, stream>>>(
            ctx_bf, wo_bf, bo + (size_t)L * D_,
            tmp, nullptr, nullptr, nullptr, nullptr, M, D_, D_);
        add_ln_kernel<<<M, 256, 0, stream>>>(tgt, tgt_bf, tmp,
            ln1_g + (size_t)L * D_, ln1_b + (size_t)L * D_);
        gemm_mfma<1><<<dim3(FF_ / 128, M / 128), 256, 0, stream>>>(
            tgt_bf, w1_bf, b1 + (size_t)L * FF_,
            nullptr, ffh_bf, nullptr, nullptr, nullptr, M, FF_, D_);
        gemm_mfma<0><<<dim3(D_ / 128, M / 128), 256, 0, stream>>>(
            ffh_bf, w2_bf, b2 + (size_t)L * D_,
            tmp, nullptr, nullptr, nullptr, nullptr, M, D_, FF_);
        add_ln_kernel<<<M, 256, 0, stream>>>(tgt, tgt_bf, tmp,
            ln2_g + (size_t)L * D_, ln2_b + (size_t)L * D_);
    }

    head_kernel<<<B_, 256, 0, stream>>>(tgt, W_ham, b_ham, head_out);
    loss_kernel<<<1, 256, 0, stream>>>(head_out, y, w, (float*)d_out);
}

// Round 3
// 2161.449 us; speedup vs baseline: 5.3029x; 1.6292x over previous
//
#include <hip/hip_runtime.h>
#include <math.h>

// ---------------------------------------------------------------------------
// TransformerContinuous: B=8, Lx=512, n_w=384, S=896, D=1024, H=16, hd=64,
// NL=4, FF=4096, HAM=144.
// Round 3: attention -> bf16 MFMA flash (Q in regs, K/Vt in LDS, P via LDS).
// ---------------------------------------------------------------------------

#define B_      8
#define LX_     512
#define NW_     384
#define S_      896
#define D_      1024
#define H_      16
#define HD_     64
#define FF_     4096
#define HAM_    144

#define RMS_SCALE 0.9999500037496876f            // 1/sqrt(1.0001)
#define PE_C     (-6.907755278982137f / 1024.0f) // -ln(1000)/D

typedef __bf16 bf16x4 __attribute__((ext_vector_type(4)));
typedef __bf16 bf16x8 __attribute__((ext_vector_type(8)));
typedef float  f32x4  __attribute__((ext_vector_type(4)));

static __device__ __forceinline__ float nan0(float v) { return (v != v) ? 0.0f : v; }

static __device__ __forceinline__ void async_copy16(const __bf16* g, __bf16* l) {
    __builtin_amdgcn_global_load_lds(
        (const __attribute__((address_space(1))) void*)g,
        (__attribute__((address_space(3))) void*)l, 16, 0, 0);
}

// ---------------- fp32 -> bf16 weight conversion (n multiple of 1024) -------
__global__ __launch_bounds__(256) void convert_kernel(
        const float* __restrict__ src, __bf16* __restrict__ dst, int n) {
    int i = (blockIdx.x * 256 + threadIdx.x) * 4;
    float4 v = *(const float4*)&src[i];
    bf16x4 o = {(__bf16)v.x, (__bf16)v.y, (__bf16)v.z, (__bf16)v.w};
    *(bf16x4*)&dst[i] = o;
}

// ---------------- embed x: rows (b,i) of x -> tgt rows 0..511 ----------------
__global__ __launch_bounds__(256) void embed_x_kernel(
        const float* __restrict__ x, const float* __restrict__ W_nail,
        const float* __restrict__ b_nail, float* __restrict__ tgt,
        __bf16* __restrict__ tgt_bf, int* __restrict__ xmask) {
    int row = blockIdx.x;              // b*512 + i
    int b = row >> 9, i = row & 511;
    const float* xr = x + (long)row * 64;
    __shared__ float xn[64];
    __shared__ float t_s;
    int tid = threadIdx.x;
    if (tid < 64) {
        float vv = xr[tid];
        float v0 = nan0(vv);
        xn[tid] = fminf(fmaxf(v0 * RMS_SCALE, -5.0f), 5.0f);
        if (tid == 0) { t_s = v0; xmask[row] = (vv != vv) ? 1 : 0; }
    }
    __syncthreads();
    float t = t_s;
    int d0 = tid * 4;
    float acc[4];
#pragma unroll
    for (int j = 0; j < 4; ++j) acc[j] = b_nail[d0 + j];
    const float* w0 = W_nail + (long)d0 * 63;
    for (int k = 0; k < 63; ++k) {
        float xv = xn[k + 1];
#pragma unroll
        for (int j = 0; j < 4; ++j) acc[j] += xv * w0[j * 63 + k];
    }
    float out[4];
#pragma unroll
    for (int j = 0; j < 4; ++j) {
        int d = d0 + j;
        float div = expf((float)(d >> 1) * PE_C);
        float ang = t * div;
        out[j] = acc[j] + ((d & 1) ? cosf(ang) : sinf(ang));
    }
    long idx = ((long)b * S_ + i) * D_ + d0;
    *(float4*)&tgt[idx] = make_float4(out[0], out[1], out[2], out[3]);
    bf16x4 ob = {(__bf16)out[0], (__bf16)out[1], (__bf16)out[2], (__bf16)out[3]};
    *(bf16x4*)&tgt_bf[idx] = ob;
}

// ---------------- embed w: rows (b,j) of w -> tgt rows 512..895 ----------------
__global__ __launch_bounds__(256) void embed_w_kernel(
        const float* __restrict__ w, const float* __restrict__ W_cond,
        const float* __restrict__ b_cond, float* __restrict__ tgt,
        __bf16* __restrict__ tgt_bf) {
    int row = blockIdx.x;              // b*384 + j
    int b = row / NW_, j = row % NW_;
    const float* wr = w + (long)row * 6;
    float wn[6];
#pragma unroll
    for (int k = 0; k < 6; ++k)
        wn[k] = fminf(fmaxf(nan0(wr[k]) * RMS_SCALE, -5.0f), 5.0f);
    int tid = threadIdx.x;
    int d0 = tid * 4;
    float pos = (float)(LX_ + j);
    float out[4];
#pragma unroll
    for (int jj = 0; jj < 4; ++jj) {
        int d = d0 + jj;
        float acc = b_cond[d];
        const float* wc = W_cond + (long)d * 6;
#pragma unroll
        for (int k = 0; k < 6; ++k) acc += wn[k] * wc[k];
        float div = expf((float)(d >> 1) * PE_C);
        float ang = pos * div;
        out[jj] = acc + ((d & 1) ? cosf(ang) : sinf(ang));
    }
    long idx = ((long)b * S_ + LX_ + j) * D_ + d0;
    *(float4*)&tgt[idx] = make_float4(out[0], out[1], out[2], out[3]);
    bf16x4 ob = {(__bf16)out[0], (__bf16)out[1], (__bf16)out[2], (__bf16)out[3]};
    *(bf16x4*)&tgt_bf[idx] = ob;
}

// ---------------- bf16 MFMA GEMM: C[M,N] = A[M,K] @ W[N,K]^T + bias ---------
// 128x128 tile, BK=32, 4 waves each computing 64x64 via 4x4 16x16x32 MFMAs.
// MODE 0: fp32 out + bias   MODE 1: bf16 out + bias + exact GELU
// MODE 2: bf16 out + bias, split to q/k/v (B,H,S,64)
template <int MODE>
__global__ __launch_bounds__(256) void gemm_mfma(
        const __bf16* __restrict__ A, const __bf16* __restrict__ W,
        const float* __restrict__ bias,
        float* __restrict__ Cf, __bf16* __restrict__ Cb,
        __bf16* __restrict__ Cq, __bf16* __restrict__ Ck, __bf16* __restrict__ Cv,
        int M, int N, int K) {
    __shared__ __bf16 As[128 * 32];
    __shared__ __bf16 Bs[128 * 32];
    int tid = threadIdx.x;
    int wave = tid >> 6, lane = tid & 63;
    int m0 = blockIdx.y * 128, n0 = blockIdx.x * 128;
    int wm = (wave >> 1) * 64, wn = (wave & 1) * 64;

    int srow = wave * 32 + (lane >> 2);
    int scol = (lane & 3) * 8;
    const __bf16* Ag = A + (size_t)(m0 + srow) * K + scol;
    const __bf16* Wg = W + (size_t)(n0 + srow) * K + scol;
    __bf16* Al = &As[wave * 1024];
    __bf16* Bl = &Bs[wave * 1024];

    f32x4 acc[4][4];
#pragma unroll
    for (int i = 0; i < 4; ++i)
#pragma unroll
        for (int j = 0; j < 4; ++j) acc[i][j] = 0.0f;

    int frow = lane & 15;
    int kg = (lane >> 4) * 8;

    for (int k0 = 0; k0 < K; k0 += 32) {
        async_copy16(Ag + k0, Al);
        async_copy16(Ag + k0 + (size_t)16 * K, Al + 512);
        async_copy16(Wg + k0, Bl);
        async_copy16(Wg + k0 + (size_t)16 * K, Bl + 512);
        __syncthreads();
        bf16x8 a[4], b[4];
#pragma unroll
        for (int mi = 0; mi < 4; ++mi)
            a[mi] = *(const bf16x8*)&As[(wm + mi * 16 + frow) * 32 + kg];
#pragma unroll
        for (int ni = 0; ni < 4; ++ni)
            b[ni] = *(const bf16x8*)&Bs[(wn + ni * 16 + frow) * 32 + kg];
#pragma unroll
        for (int mi = 0; mi < 4; ++mi)
#pragma unroll
            for (int ni = 0; ni < 4; ++ni)
                acc[mi][ni] = __builtin_amdgcn_mfma_f32_16x16x32_bf16(
                    a[mi], b[ni], acc[mi][ni], 0, 0, 0);
        __syncthreads();
    }

    int col_l = lane & 15;
    int rquad = (lane >> 4) * 4;
#pragma unroll
    for (int ni = 0; ni < 4; ++ni) {
        int cg = n0 + wn + ni * 16 + col_l;
        float bv = bias[cg];
#pragma unroll
        for (int mi = 0; mi < 4; ++mi) {
#pragma unroll
            for (int r = 0; r < 4; ++r) {
                int rg = m0 + wm + mi * 16 + rquad + r;
                float v = acc[mi][ni][r] + bv;
                if (MODE == 0) {
                    Cf[(size_t)rg * N + cg] = v;
                } else if (MODE == 1) {
                    v = 0.5f * v * (1.0f + erff(v * 0.7071067811865476f));
                    Cb[(size_t)rg * N + cg] = (__bf16)v;
                } else {
                    int which = cg >> 10;        // 0=q 1=k 2=v
                    int h = (cg & 1023) >> 6;
                    int e = cg & 63;
                    int bb = rg / S_, s = rg % S_;
                    __bf16* dst = (which == 0) ? Cq : (which == 1) ? Ck : Cv;
                    dst[(((size_t)bb * H_ + h) * S_ + s) * HD_ + e] = (__bf16)v;
                }
            }
        }
    }
}

// ---------------- MFMA flash attention (bf16 in, bf16 ctx out) --------------
// Block: one (b,h) x 64 q rows; 4 waves x 16 q rows. Iterate 64-key tiles.
__global__ __launch_bounds__(256) void attn_mfma(
        const __bf16* __restrict__ q, const __bf16* __restrict__ k,
        const __bf16* __restrict__ v, const int* __restrict__ xmask,
        __bf16* __restrict__ ctx) {
    __shared__ __bf16 Ks[64][72];
    __shared__ __bf16 Vt[64][66];       // Vt[d][k]
    __shared__ __bf16 Ps[4][16][72];    // per-wave P in A-layout
    __shared__ float mb[LX_];           // x-mask bias: 0 or -inf
    int tid = threadIdx.x;
    int wave = tid >> 6, lane = tid & 63;
    int frow = lane & 15, quad = lane >> 4;
    int blk = blockIdx.x;
    int qt = blk % 14;
    int bh = blk / 14;
    int b = bh >> 4, h = bh & 15;
    int q0 = qt * 64;
    int q0w = q0 + wave * 16;
    size_t base = (size_t)bh * S_ * HD_;

    for (int i = tid; i < LX_; i += 256)
        mb[i] = xmask[(b << 9) + i] ? -INFINITY : 0.0f;

    // Q fragments (persist in registers)
    const __bf16* qrow = q + base + (size_t)(q0w + frow) * HD_ + quad * 8;
    bf16x8 aq0 = *(const bf16x8*)qrow;
    bf16x8 aq1 = *(const bf16x8*)(qrow + 32);

    f32x4 o[4];
#pragma unroll
    for (int dt = 0; dt < 4; ++dt) o[dt] = 0.0f;
    float mrow[4] = {-INFINITY, -INFINITY, -INFINITY, -INFINITY};
    float lrow[4] = {0.0f, 0.0f, 0.0f, 0.0f};

    int kend = (q0 >= LX_) ? (q0 + 64) : LX_;

    // staging indices
    int sr = tid >> 2;                  // 0..63 key row
    int sc = (tid & 3) * 8;             // 0,8,16,24
    const __bf16* kg = k + base + (size_t)sr * HD_ + sc;
    const __bf16* vg = v + base + (size_t)sr * HD_ + sc;

    for (int k0 = 0; k0 < kend; k0 += 64) {
        // stage K tile + transposed V tile
        {
            size_t off = (size_t)k0 * HD_;
            bf16x8 k0v = *(const bf16x8*)(kg + off);
            bf16x8 k1v = *(const bf16x8*)(kg + off + 32);
            *(bf16x8*)&Ks[sr][sc] = k0v;
            *(bf16x8*)&Ks[sr][sc + 32] = k1v;
            bf16x8 v0v = *(const bf16x8*)(vg + off);
            bf16x8 v1v = *(const bf16x8*)(vg + off + 32);
#pragma unroll
            for (int j = 0; j < 8; ++j) {
                Vt[sc + j][sr] = v0v[j];
                Vt[sc + 32 + j][sr] = v1v[j];
            }
        }
        __syncthreads();

        // QK^T: scores for 16 q rows x 64 keys
        f32x4 scr[4];
#pragma unroll
        for (int nt = 0; nt < 4; ++nt) {
            bf16x8 bk0 = *(const bf16x8*)&Ks[nt * 16 + frow][quad * 8];
            bf16x8 bk1 = *(const bf16x8*)&Ks[nt * 16 + frow][32 + quad * 8];
            f32x4 z = 0.0f;
            z = __builtin_amdgcn_mfma_f32_16x16x32_bf16(aq0, bk0, z, 0, 0, 0);
            z = __builtin_amdgcn_mfma_f32_16x16x32_bf16(aq1, bk1, z, 0, 0, 0);
            scr[nt] = z;
        }

        // mask + scale, row max
        float tmax[4] = {-INFINITY, -INFINITY, -INFINITY, -INFINITY};
#pragma unroll
        for (int nt = 0; nt < 4; ++nt) {
            int kj = k0 + nt * 16 + frow;
            float bias = (kj < LX_) ? mb[kj] : 0.0f;
#pragma unroll
            for (int r = 0; r < 4; ++r) {
                float s = scr[nt][r] * 0.125f + bias;
                if (kj >= LX_ && kj > q0w + quad * 4 + r) s = -INFINITY;
                scr[nt][r] = s;
                tmax[r] = fmaxf(tmax[r], s);
            }
        }
#pragma unroll
        for (int off = 1; off < 16; off <<= 1)
#pragma unroll
            for (int r = 0; r < 4; ++r)
                tmax[r] = fmaxf(tmax[r], __shfl_xor(tmax[r], off, 64));

        // online softmax update
        float alpha[4], rsum[4];
#pragma unroll
        for (int r = 0; r < 4; ++r) {
            float nm = fmaxf(mrow[r], tmax[r]);
            alpha[r] = (nm == -INFINITY) ? 1.0f : __expf(mrow[r] - nm);
            mrow[r] = nm;
            rsum[r] = 0.0f;
        }
#pragma unroll
        for (int nt = 0; nt < 4; ++nt) {
#pragma unroll
            for (int r = 0; r < 4; ++r) {
                float s = scr[nt][r];
                float p = (s == -INFINITY) ? 0.0f : __expf(s - mrow[r]);
                rsum[r] += p;
                Ps[wave][quad * 4 + r][nt * 16 + frow] = (__bf16)p;
            }
        }
#pragma unroll
        for (int off = 1; off < 16; off <<= 1)
#pragma unroll
            for (int r = 0; r < 4; ++r)
                rsum[r] += __shfl_xor(rsum[r], off, 64);
#pragma unroll
        for (int r = 0; r < 4; ++r)
            lrow[r] = lrow[r] * alpha[r] + rsum[r];
#pragma unroll
        for (int dt = 0; dt < 4; ++dt)
#pragma unroll
            for (int r = 0; r < 4; ++r)
                o[dt][r] *= alpha[r];

        // PV: A = P (own wave's LDS), B = Vt
        bf16x8 ap0 = *(const bf16x8*)&Ps[wave][frow][quad * 8];
        bf16x8 ap1 = *(const bf16x8*)&Ps[wave][frow][32 + quad * 8];
#pragma unroll
        for (int dt = 0; dt < 4; ++dt) {
            bf16x8 bv0 = *(const bf16x8*)&Vt[dt * 16 + frow][quad * 8];
            bf16x8 bv1 = *(const bf16x8*)&Vt[dt * 16 + frow][32 + quad * 8];
            o[dt] = __builtin_amdgcn_mfma_f32_16x16x32_bf16(ap0, bv0, o[dt], 0, 0, 0);
            o[dt] = __builtin_amdgcn_mfma_f32_16x16x32_bf16(ap1, bv1, o[dt], 0, 0, 0);
        }
        __syncthreads();
    }

    // epilogue: ctx[b, q, h*64 + d]
#pragma unroll
    for (int r = 0; r < 4; ++r) {
        float inv = (lrow[r] > 0.0f) ? 1.0f / lrow[r] : 0.0f;
        int qg = q0w + quad * 4 + r;
        size_t ob = ((size_t)b * S_ + qg) * D_ + h * HD_;
#pragma unroll
        for (int dt = 0; dt < 4; ++dt)
            ctx[ob + dt * 16 + frow] = (__bf16)(o[dt][r] * inv);
    }
}

// ---------------- fused residual add + LayerNorm (fp32 + bf16 mirror) -------
__global__ __launch_bounds__(256) void add_ln_kernel(
        float* __restrict__ xs, __bf16* __restrict__ xs_bf,
        const float* __restrict__ o,
        const float* __restrict__ g, const float* __restrict__ bb) {
    long row = blockIdx.x;
    float* xr = xs + row * D_;
    const float* orr = o + row * D_;
    int tid = threadIdx.x;
    float4 a = *(const float4*)&xr[tid * 4];
    float4 b = *(const float4*)&orr[tid * 4];
    float vv[4] = {a.x + b.x, a.y + b.y, a.z + b.z, a.w + b.w};
    float s = vv[0] + vv[1] + vv[2] + vv[3];
    __shared__ float red[4];
    __shared__ float stat;
#pragma unroll
    for (int off = 32; off; off >>= 1) s += __shfl_down(s, off, 64);
    if ((tid & 63) == 0) red[tid >> 6] = s;
    __syncthreads();
    if (tid == 0) stat = (red[0] + red[1] + red[2] + red[3]) * (1.0f / 1024.0f);
    __syncthreads();
    float mean = stat;
    float d[4];
    float s2 = 0.0f;
#pragma unroll
    for (int j = 0; j < 4; ++j) { d[j] = vv[j] - mean; s2 += d[j] * d[j]; }
    __syncthreads();
#pragma unroll
    for (int off = 32; off; off >>= 1) s2 += __shfl_down(s2, off, 64);
    if ((tid & 63) == 0) red[tid >> 6] = s2;
    __syncthreads();
    if (tid == 0) stat = (red[0] + red[1] + red[2] + red[3]) * (1.0f / 1024.0f);
    __syncthreads();
    float inv = 1.0f / sqrtf(stat + 1e-5f);
    float4 gg = *(const float4*)&g[tid * 4];
    float4 bv = *(const float4*)&bb[tid * 4];
    float g4[4] = {gg.x, gg.y, gg.z, gg.w};
    float b4[4] = {bv.x, bv.y, bv.z, bv.w};
    float out[4];
#pragma unroll
    for (int j = 0; j < 4; ++j) out[j] = d[j] * inv * g4[j] + b4[j];
    *(float4*)&xr[tid * 4] = make_float4(out[0], out[1], out[2], out[3]);
    bf16x4 ob = {(__bf16)out[0], (__bf16)out[1], (__bf16)out[2], (__bf16)out[3]};
    *(bf16x4*)&xs_bf[row * D_ + tid * 4] = ob;
}

// ---------------- head: (8,1024) @ W_ham^T + b_ham -> (8,144) ----------------
__global__ __launch_bounds__(256) void head_kernel(
        const float* __restrict__ tgt, const float* __restrict__ W_ham,
        const float* __restrict__ b_ham, float* __restrict__ out) {
    int b = blockIdx.x;
    int tid = threadIdx.x;
    __shared__ float xr[D_];
    const float* row = tgt + ((long)b * S_ + (S_ - 1)) * D_;
    for (int i = tid; i < D_; i += 256) xr[i] = row[i];
    __syncthreads();
    for (int n = tid; n < HAM_; n += 256) {
        float acc = b_ham[n];
        const float* wr = W_ham + (long)n * D_;
        for (int kk = 0; kk < D_; ++kk) acc += xr[kk] * wr[kk];
        out[b * HAM_ + n] = acc;
    }
}

// ---------------- loss: mean((head_out - (y - w_last))^2) --------------------
__global__ __launch_bounds__(256) void loss_kernel(
        const float* __restrict__ head_out, const float* __restrict__ y,
        const float* __restrict__ w, float* __restrict__ out) {
    int tid = threadIdx.x;
    float acc = 0.0f;
    for (int i = tid; i < B_ * HAM_; i += 256) {
        int b = i / HAM_, r = i % HAM_;
        float w_last = w[((long)b * 16 + 15) * HAM_ + r];
        float resid = y[i] - w_last;
        float dd = head_out[i] - resid;
        acc += dd * dd;
    }
    __shared__ float red[4];
#pragma unroll
    for (int off = 32; off; off >>= 1) acc += __shfl_down(acc, off, 64);
    if ((tid & 63) == 0) red[tid >> 6] = acc;
    __syncthreads();
    if (tid == 0)
        out[0] = (red[0] + red[1] + red[2] + red[3]) * (1.0f / (B_ * HAM_));
}

// ---------------------------------------------------------------------------
extern "C" void kernel_launch(void* const* d_in, const int* in_sizes, int n_in,
                              void* d_out, int out_size, void* d_ws, size_t ws_size,
                              hipStream_t stream) {
    const float* x      = (const float*)d_in[0];
    const float* w      = (const float*)d_in[1];
    const float* y      = (const float*)d_in[2];
    const float* W_nail = (const float*)d_in[3];
    const float* b_nail = (const float*)d_in[4];
    const float* W_cond = (const float*)d_in[5];
    const float* b_cond = (const float*)d_in[6];
    const float* Wqkv   = (const float*)d_in[7];
    const float* bqkv   = (const float*)d_in[8];
    const float* Wo     = (const float*)d_in[9];
    const float* bo     = (const float*)d_in[10];
    const float* ln1_g  = (const float*)d_in[11];
    const float* ln1_b  = (const float*)d_in[12];
    const float* ln2_g  = (const float*)d_in[13];
    const float* ln2_b  = (const float*)d_in[14];
    const float* W1     = (const float*)d_in[15];
    const float* b1     = (const float*)d_in[16];
    const float* W2     = (const float*)d_in[17];
    const float* b2     = (const float*)d_in[18];
    const float* W_ham  = (const float*)d_in[19];
    const float* b_ham  = (const float*)d_in[20];

    float* ws = (float*)d_ws;
    const long SEG = (long)B_ * S_ * D_;            // 7,340,032 floats
    float*  tgt    = ws;                            // [0, SEG)
    float*  tmp    = ws + SEG;                      // [SEG, 2SEG)
    __bf16* tgt_bf = (__bf16*)(ws + 2 * SEG);       // [2SEG, 2.5SEG)
    __bf16* ctx_bf = (__bf16*)(ws + 2 * SEG + SEG / 2);      // [2.5SEG, 3SEG)
    __bf16* qb     = (__bf16*)(ws + 3 * SEG);                // [3SEG, 3.5SEG)
    __bf16* kb     = (__bf16*)(ws + 3 * SEG + SEG / 2);      // [3.5SEG, 4SEG)
    __bf16* vb     = (__bf16*)(ws + 4 * SEG);                // [4SEG, 4.5SEG)
    __bf16* ffh_bf = (__bf16*)(ws + 2 * SEG + SEG / 2);      // overlays ctx|q|k|v
    __bf16* wbf    = (__bf16*)(ws + 4 * SEG + SEG / 2);      // 12.58M bf16
    int*    xmask    = (int*)(ws + 4 * SEG + SEG / 2 + 6291456);
    float*  head_out = ws + 4 * SEG + SEG / 2 + 6291456 + 4096;

    __bf16* wqkv_bf = wbf;
    __bf16* wo_bf   = wbf + 3145728;
    __bf16* w1_bf   = wbf + 4194304;
    __bf16* w2_bf   = wbf + 8388608;

    const int M = B_ * S_;                          // 7168

    embed_x_kernel<<<B_ * LX_, 256, 0, stream>>>(x, W_nail, b_nail, tgt, tgt_bf, xmask);
    embed_w_kernel<<<B_ * NW_, 256, 0, stream>>>(w, W_cond, b_cond, tgt, tgt_bf);

    for (int L = 0; L < 4; ++L) {
        const int NQ = 3 * D_ * D_, NO = D_ * D_, N1 = FF_ * D_, N2 = D_ * FF_;
        convert_kernel<<<NQ / 1024, 256, 0, stream>>>(Wqkv + (size_t)L * NQ, wqkv_bf, NQ);
        convert_kernel<<<NO / 1024, 256, 0, stream>>>(Wo   + (size_t)L * NO, wo_bf,   NO);
        convert_kernel<<<N1 / 1024, 256, 0, stream>>>(W1   + (size_t)L * N1, w1_bf,   N1);
        convert_kernel<<<N2 / 1024, 256, 0, stream>>>(W2   + (size_t)L * N2, w2_bf,   N2);

        gemm_mfma<2><<<dim3(3 * D_ / 128, M / 128), 256, 0, stream>>>(
            tgt_bf, wqkv_bf, bqkv + (size_t)L * 3 * D_,
            nullptr, nullptr, qb, kb, vb, M, 3 * D_, D_);
        attn_mfma<<<B_ * H_ * (S_ / 64), 256, 0, stream>>>(qb, kb, vb, xmask, ctx_bf);
        gemm_mfma<0><<<dim3(D_ / 128, M / 128), 256, 0, stream>>>(
            ctx_bf, wo_bf, bo + (size_t)L * D_,
            tmp, nullptr, nullptr, nullptr, nullptr, M, D_, D_);
        add_ln_kernel<<<M, 256, 0, stream>>>(tgt, tgt_bf, tmp,
            ln1_g + (size_t)L * D_, ln1_b + (size_t)L * D_);
        gemm_mfma<1><<<dim3(FF_ / 128, M / 128), 256, 0, stream>>>(
            tgt_bf, w1_bf, b1 + (size_t)L * FF_,
            nullptr, ffh_bf, nullptr, nullptr, nullptr, M, FF_, D_);
        gemm_mfma<0><<<dim3(D_ / 128, M / 128), 256, 0, stream>>>(
            ffh_bf, w2_bf, b2 + (size_t)L * D_,
            tmp, nullptr, nullptr, nullptr, nullptr, M, D_, FF_);
        add_ln_kernel<<<M, 256, 0, stream>>>(tgt, tgt_bf, tmp,
            ln2_g + (size_t)L * D_, ln2_b + (size_t)L * D_);
    }

    head_kernel<<<B_, 256, 0, stream>>>(tgt, W_ham, b_ham, head_out);
    loss_kernel<<<1, 256, 0, stream>>>(head_out, y, w, (float*)d_out);
}

// Round 4
// 2160.012 us; speedup vs baseline: 5.3064x; 1.0007x over previous
//
#include <hip/hip_runtime.h>
#include <math.h>

// ---------------------------------------------------------------------------
// TransformerContinuous: B=8, Lx=512, n_w=384, S=896, D=1024, H=16, hd=64,
// NL=4, FF=4096, HAM=144.
// Round 4: GEMM epilogue vectorized via MFMA operand swap (lane holds 4
// consecutive N-cols), fast tanh-GELU, fused weight conversion.
// ---------------------------------------------------------------------------

#define B_      8
#define LX_     512
#define NW_     384
#define S_      896
#define D_      1024
#define H_      16
#define HD_     64
#define FF_     4096
#define HAM_    144

#define RMS_SCALE 0.9999500037496876f            // 1/sqrt(1.0001)
#define PE_C     (-6.907755278982137f / 1024.0f) // -ln(1000)/D

typedef __bf16 bf16x4 __attribute__((ext_vector_type(4)));
typedef __bf16 bf16x8 __attribute__((ext_vector_type(8)));
typedef float  f32x4  __attribute__((ext_vector_type(4)));

static __device__ __forceinline__ float nan0(float v) { return (v != v) ? 0.0f : v; }

static __device__ __forceinline__ void async_copy16(const __bf16* g, __bf16* l) {
    __builtin_amdgcn_global_load_lds(
        (const __attribute__((address_space(1))) void*)g,
        (__attribute__((address_space(3))) void*)l, 16, 0, 0);
}

// tanh-form GELU, one v_exp_f32; |err| vs exact-erf GELU < ~3e-4 (sub-bf16-ulp)
static __device__ __forceinline__ float fast_gelu(float x) {
    float x3 = x * x * x;
    float z = 0.7978845608028654f * x + 0.035677408136300125f * x3;
    float az = fabsf(z);
    float e = __expf(2.0f * az);
    float t = 1.0f - 2.0f / (e + 1.0f);
    t = (z < 0.0f) ? -t : t;
    return 0.5f * x * (1.0f + t);
}

// ---------------- fused fp32 -> bf16 conversion of 4 weight tensors ---------
// sizes: 3145728 | 1048576 | 4194304 | 4194304 elems -> 12288 blocks x 1024
__global__ __launch_bounds__(256) void convert4_kernel(
        const float* __restrict__ s0, const float* __restrict__ s1,
        const float* __restrict__ s2, const float* __restrict__ s3,
        __bf16* __restrict__ d0, __bf16* __restrict__ d1,
        __bf16* __restrict__ d2, __bf16* __restrict__ d3) {
    int blk = blockIdx.x;
    const float* src; __bf16* dst; int base;
    if (blk < 3072)      { src = s0; dst = d0; base = blk; }
    else if (blk < 4096) { src = s1; dst = d1; base = blk - 3072; }
    else if (blk < 8192) { src = s2; dst = d2; base = blk - 4096; }
    else                 { src = s3; dst = d3; base = blk - 8192; }
    int i = (base * 256 + threadIdx.x) * 4;
    float4 v = *(const float4*)&src[i];
    bf16x4 o = {(__bf16)v.x, (__bf16)v.y, (__bf16)v.z, (__bf16)v.w};
    *(bf16x4*)&dst[i] = o;
}

// ---------------- embed x: rows (b,i) of x -> tgt rows 0..511 ----------------
__global__ __launch_bounds__(256) void embed_x_kernel(
        const float* __restrict__ x, const float* __restrict__ W_nail,
        const float* __restrict__ b_nail, float* __restrict__ tgt,
        __bf16* __restrict__ tgt_bf, int* __restrict__ xmask) {
    int row = blockIdx.x;              // b*512 + i
    int b = row >> 9, i = row & 511;
    const float* xr = x + (long)row * 64;
    __shared__ float xn[64];
    __shared__ float t_s;
    int tid = threadIdx.x;
    if (tid < 64) {
        float vv = xr[tid];
        float v0 = nan0(vv);
        xn[tid] = fminf(fmaxf(v0 * RMS_SCALE, -5.0f), 5.0f);
        if (tid == 0) { t_s = v0; xmask[row] = (vv != vv) ? 1 : 0; }
    }
    __syncthreads();
    float t = t_s;
    int d0 = tid * 4;
    float acc[4];
#pragma unroll
    for (int j = 0; j < 4; ++j) acc[j] = b_nail[d0 + j];
    const float* w0 = W_nail + (long)d0 * 63;
    for (int k = 0; k < 63; ++k) {
        float xv = xn[k + 1];
#pragma unroll
        for (int j = 0; j < 4; ++j) acc[j] += xv * w0[j * 63 + k];
    }
    float out[4];
#pragma unroll
    for (int j = 0; j < 4; ++j) {
        int d = d0 + j;
        float div = expf((float)(d >> 1) * PE_C);
        float ang = t * div;
        out[j] = acc[j] + ((d & 1) ? cosf(ang) : sinf(ang));
    }
    long idx = ((long)b * S_ + i) * D_ + d0;
    *(float4*)&tgt[idx] = make_float4(out[0], out[1], out[2], out[3]);
    bf16x4 ob = {(__bf16)out[0], (__bf16)out[1], (__bf16)out[2], (__bf16)out[3]};
    *(bf16x4*)&tgt_bf[idx] = ob;
}

// ---------------- embed w: rows (b,j) of w -> tgt rows 512..895 ----------------
__global__ __launch_bounds__(256) void embed_w_kernel(
        const float* __restrict__ w, const float* __restrict__ W_cond,
        const float* __restrict__ b_cond, float* __restrict__ tgt,
        __bf16* __restrict__ tgt_bf) {
    int row = blockIdx.x;              // b*384 + j
    int b = row / NW_, j = row % NW_;
    const float* wr = w + (long)row * 6;
    float wn[6];
#pragma unroll
    for (int k = 0; k < 6; ++k)
        wn[k] = fminf(fmaxf(nan0(wr[k]) * RMS_SCALE, -5.0f), 5.0f);
    int tid = threadIdx.x;
    int d0 = tid * 4;
    float pos = (float)(LX_ + j);
    float out[4];
#pragma unroll
    for (int jj = 0; jj < 4; ++jj) {
        int d = d0 + jj;
        float acc = b_cond[d];
        const float* wc = W_cond + (long)d * 6;
#pragma unroll
        for (int k = 0; k < 6; ++k) acc += wn[k] * wc[k];
        float div = expf((float)(d >> 1) * PE_C);
        float ang = pos * div;
        out[jj] = acc + ((d & 1) ? cosf(ang) : sinf(ang));
    }
    long idx = ((long)b * S_ + LX_ + j) * D_ + d0;
    *(float4*)&tgt[idx] = make_float4(out[0], out[1], out[2], out[3]);
    bf16x4 ob = {(__bf16)out[0], (__bf16)out[1], (__bf16)out[2], (__bf16)out[3]};
    *(bf16x4*)&tgt_bf[idx] = ob;
}

// ---------------- bf16 MFMA GEMM: C[M,N] = A[M,K] @ W[N,K]^T + bias ---------
// 128x128 tile, BK=32, 4 waves each computing 64x64 via 4x4 16x16x32 MFMAs.
// MFMA operands SWAPPED (mfma(b,a,acc)): D-row(quad*4+r)=n, D-col(lane&15)=m,
// so each lane holds 4 consecutive n-cols per acc -> vectorized stores.
// MODE 0: fp32 out + bias   MODE 1: bf16 out + bias + fast GELU
// MODE 2: bf16 out + bias, split to q/k/v (B,H,S,64)
template <int MODE>
__global__ __launch_bounds__(256) void gemm_mfma(
        const __bf16* __restrict__ A, const __bf16* __restrict__ W,
        const float* __restrict__ bias,
        float* __restrict__ Cf, __bf16* __restrict__ Cb,
        __bf16* __restrict__ Cq, __bf16* __restrict__ Ck, __bf16* __restrict__ Cv,
        int M, int N, int K) {
    __shared__ __bf16 As[128 * 32];
    __shared__ __bf16 Bs[128 * 32];
    int tid = threadIdx.x;
    int wave = tid >> 6, lane = tid & 63;
    int m0 = blockIdx.y * 128, n0 = blockIdx.x * 128;
    int wm = (wave >> 1) * 64, wn = (wave & 1) * 64;

    int srow = wave * 32 + (lane >> 2);
    int scol = (lane & 3) * 8;
    const __bf16* Ag = A + (size_t)(m0 + srow) * K + scol;
    const __bf16* Wg = W + (size_t)(n0 + srow) * K + scol;
    __bf16* Al = &As[wave * 1024];
    __bf16* Bl = &Bs[wave * 1024];

    f32x4 acc[4][4];
#pragma unroll
    for (int i = 0; i < 4; ++i)
#pragma unroll
        for (int j = 0; j < 4; ++j) acc[i][j] = 0.0f;

    int frow = lane & 15;
    int kg = (lane >> 4) * 8;

    for (int k0 = 0; k0 < K; k0 += 32) {
        async_copy16(Ag + k0, Al);
        async_copy16(Ag + k0 + (size_t)16 * K, Al + 512);
        async_copy16(Wg + k0, Bl);
        async_copy16(Wg + k0 + (size_t)16 * K, Bl + 512);
        __syncthreads();
        bf16x8 a[4], b[4];
#pragma unroll
        for (int mi = 0; mi < 4; ++mi)
            a[mi] = *(const bf16x8*)&As[(wm + mi * 16 + frow) * 32 + kg];
#pragma unroll
        for (int ni = 0; ni < 4; ++ni)
            b[ni] = *(const bf16x8*)&Bs[(wn + ni * 16 + frow) * 32 + kg];
#pragma unroll
        for (int mi = 0; mi < 4; ++mi)
#pragma unroll
            for (int ni = 0; ni < 4; ++ni)
                acc[mi][ni] = __builtin_amdgcn_mfma_f32_16x16x32_bf16(
                    b[ni], a[mi], acc[mi][ni], 0, 0, 0);
        __syncthreads();
    }

    // epilogue (swapped layout): m = lane&15, n = quad*4 + r
    int mrow_l = lane & 15;
    int nq = (lane >> 4) * 4;
#pragma unroll
    for (int ni = 0; ni < 4; ++ni) {
        int cg0 = n0 + wn + ni * 16 + nq;
        float4 bv = *(const float4*)&bias[cg0];
        float bz[4] = {bv.x, bv.y, bv.z, bv.w};
#pragma unroll
        for (int mi = 0; mi < 4; ++mi) {
            int rg = m0 + wm + mi * 16 + mrow_l;
            float vv[4];
#pragma unroll
            for (int r = 0; r < 4; ++r) {
                float v = acc[mi][ni][r] + bz[r];
                if (MODE == 1) v = fast_gelu(v);
                vv[r] = v;
            }
            if (MODE == 0) {
                *(float4*)&Cf[(size_t)rg * N + cg0] =
                    make_float4(vv[0], vv[1], vv[2], vv[3]);
            } else if (MODE == 1) {
                bf16x4 o = {(__bf16)vv[0], (__bf16)vv[1], (__bf16)vv[2], (__bf16)vv[3]};
                *(bf16x4*)&Cb[(size_t)rg * N + cg0] = o;
            } else {
                int which = cg0 >> 10;        // 0=q 1=k 2=v
                int h = (cg0 & 1023) >> 6;
                int e = cg0 & 63;             // multiple of 4, stays in-head
                int bb = rg / S_, s = rg % S_;
                __bf16* dst = (which == 0) ? Cq : (which == 1) ? Ck : Cv;
                bf16x4 o = {(__bf16)vv[0], (__bf16)vv[1], (__bf16)vv[2], (__bf16)vv[3]};
                *(bf16x4*)&dst[(((size_t)bb * H_ + h) * S_ + s) * HD_ + e] = o;
            }
        }
    }
}

// ---------------- MFMA flash attention (bf16 in, bf16 ctx out) --------------
// Block: one (b,h) x 64 q rows; 4 waves x 16 q rows. Iterate 64-key tiles.
__global__ __launch_bounds__(256) void attn_mfma(
        const __bf16* __restrict__ q, const __bf16* __restrict__ k,
        const __bf16* __restrict__ v, const int* __restrict__ xmask,
        __bf16* __restrict__ ctx) {
    __shared__ __bf16 Ks[64][72];
    __shared__ __bf16 Vt[64][66];       // Vt[d][k]
    __shared__ __bf16 Ps[4][16][72];    // per-wave P in A-layout
    __shared__ float mb[LX_];           // x-mask bias: 0 or -inf
    int tid = threadIdx.x;
    int wave = tid >> 6, lane = tid & 63;
    int frow = lane & 15, quad = lane >> 4;
    int blk = blockIdx.x;
    int qt = blk % 14;
    int bh = blk / 14;
    int b = bh >> 4, h = bh & 15;
    int q0 = qt * 64;
    int q0w = q0 + wave * 16;
    size_t base = (size_t)bh * S_ * HD_;

    for (int i = tid; i < LX_; i += 256)
        mb[i] = xmask[(b << 9) + i] ? -INFINITY : 0.0f;

    const __bf16* qrow = q + base + (size_t)(q0w + frow) * HD_ + quad * 8;
    bf16x8 aq0 = *(const bf16x8*)qrow;
    bf16x8 aq1 = *(const bf16x8*)(qrow + 32);

    f32x4 o[4];
#pragma unroll
    for (int dt = 0; dt < 4; ++dt) o[dt] = 0.0f;
    float mrow[4] = {-INFINITY, -INFINITY, -INFINITY, -INFINITY};
    float lrow[4] = {0.0f, 0.0f, 0.0f, 0.0f};

    int kend = (q0 >= LX_) ? (q0 + 64) : LX_;

    int sr = tid >> 2;
    int sc = (tid & 3) * 8;
    const __bf16* kg = k + base + (size_t)sr * HD_ + sc;
    const __bf16* vg = v + base + (size_t)sr * HD_ + sc;

    for (int k0 = 0; k0 < kend; k0 += 64) {
        {
            size_t off = (size_t)k0 * HD_;
            bf16x8 k0v = *(const bf16x8*)(kg + off);
            bf16x8 k1v = *(const bf16x8*)(kg + off + 32);
            *(bf16x8*)&Ks[sr][sc] = k0v;
            *(bf16x8*)&Ks[sr][sc + 32] = k1v;
            bf16x8 v0v = *(const bf16x8*)(vg + off);
            bf16x8 v1v = *(const bf16x8*)(vg + off + 32);
#pragma unroll
            for (int j = 0; j < 8; ++j) {
                Vt[sc + j][sr] = v0v[j];
                Vt[sc + 32 + j][sr] = v1v[j];
            }
        }
        __syncthreads();

        f32x4 scr[4];
#pragma unroll
        for (int nt = 0; nt < 4; ++nt) {
            bf16x8 bk0 = *(const bf16x8*)&Ks[nt * 16 + frow][quad * 8];
            bf16x8 bk1 = *(const bf16x8*)&Ks[nt * 16 + frow][32 + quad * 8];
            f32x4 z = 0.0f;
            z = __builtin_amdgcn_mfma_f32_16x16x32_bf16(aq0, bk0, z, 0, 0, 0);
            z = __builtin_amdgcn_mfma_f32_16x16x32_bf16(aq1, bk1, z, 0, 0, 0);
            scr[nt] = z;
        }

        float tmax[4] = {-INFINITY, -INFINITY, -INFINITY, -INFINITY};
#pragma unroll
        for (int nt = 0; nt < 4; ++nt) {
            int kj = k0 + nt * 16 + frow;
            float bias = (kj < LX_) ? mb[kj] : 0.0f;
#pragma unroll
            for (int r = 0; r < 4; ++r) {
                float s = scr[nt][r] * 0.125f + bias;
                if (kj >= LX_ && kj > q0w + quad * 4 + r) s = -INFINITY;
                scr[nt][r] = s;
                tmax[r] = fmaxf(tmax[r], s);
            }
        }
#pragma unroll
        for (int off = 1; off < 16; off <<= 1)
#pragma unroll
            for (int r = 0; r < 4; ++r)
                tmax[r] = fmaxf(tmax[r], __shfl_xor(tmax[r], off, 64));

        float alpha[4], rsum[4];
#pragma unroll
        for (int r = 0; r < 4; ++r) {
            float nm = fmaxf(mrow[r], tmax[r]);
            alpha[r] = (nm == -INFINITY) ? 1.0f : __expf(mrow[r] - nm);
            mrow[r] = nm;
            rsum[r] = 0.0f;
        }
#pragma unroll
        for (int nt = 0; nt < 4; ++nt) {
#pragma unroll
            for (int r = 0; r < 4; ++r) {
                float s = scr[nt][r];
                float p = (s == -INFINITY) ? 0.0f : __expf(s - mrow[r]);
                rsum[r] += p;
                Ps[wave][quad * 4 + r][nt * 16 + frow] = (__bf16)p;
            }
        }
#pragma unroll
        for (int off = 1; off < 16; off <<= 1)
#pragma unroll
            for (int r = 0; r < 4; ++r)
                rsum[r] += __shfl_xor(rsum[r], off, 64);
#pragma unroll
        for (int r = 0; r < 4; ++r)
            lrow[r] = lrow[r] * alpha[r] + rsum[r];
#pragma unroll
        for (int dt = 0; dt < 4; ++dt)
#pragma unroll
            for (int r = 0; r < 4; ++r)
                o[dt][r] *= alpha[r];

        bf16x8 ap0 = *(const bf16x8*)&Ps[wave][frow][quad * 8];
        bf16x8 ap1 = *(const bf16x8*)&Ps[wave][frow][32 + quad * 8];
#pragma unroll
        for (int dt = 0; dt < 4; ++dt) {
            bf16x8 bv0 = *(const bf16x8*)&Vt[dt * 16 + frow][quad * 8];
            bf16x8 bv1 = *(const bf16x8*)&Vt[dt * 16 + frow][32 + quad * 8];
            o[dt] = __builtin_amdgcn_mfma_f32_16x16x32_bf16(ap0, bv0, o[dt], 0, 0, 0);
            o[dt] = __builtin_amdgcn_mfma_f32_16x16x32_bf16(ap1, bv1, o[dt], 0, 0, 0);
        }
        __syncthreads();
    }

#pragma unroll
    for (int r = 0; r < 4; ++r) {
        float inv = (lrow[r] > 0.0f) ? 1.0f / lrow[r] : 0.0f;
        int qg = q0w + quad * 4 + r;
        size_t ob = ((size_t)b * S_ + qg) * D_ + h * HD_;
#pragma unroll
        for (int dt = 0; dt < 4; ++dt)
            ctx[ob + dt * 16 + frow] = (__bf16)(o[dt][r] * inv);
    }
}

// ---------------- fused residual add + LayerNorm (fp32 + bf16 mirror) -------
__global__ __launch_bounds__(256) void add_ln_kernel(
        float* __restrict__ xs, __bf16* __restrict__ xs_bf,
        const float* __restrict__ o,
        const float* __restrict__ g, const float* __restrict__ bb) {
    long row = blockIdx.x;
    float* xr = xs + row * D_;
    const float* orr = o + row * D_;
    int tid = threadIdx.x;
    float4 a = *(const float4*)&xr[tid * 4];
    float4 b = *(const float4*)&orr[tid * 4];
    float vv[4] = {a.x + b.x, a.y + b.y, a.z + b.z, a.w + b.w};
    float s = vv[0] + vv[1] + vv[2] + vv[3];
    __shared__ float red[4];
    __shared__ float stat;
#pragma unroll
    for (int off = 32; off; off >>= 1) s += __shfl_down(s, off, 64);
    if ((tid & 63) == 0) red[tid >> 6] = s;
    __syncthreads();
    if (tid == 0) stat = (red[0] + red[1] + red[2] + red[3]) * (1.0f / 1024.0f);
    __syncthreads();
    float mean = stat;
    float d[4];
    float s2 = 0.0f;
#pragma unroll
    for (int j = 0; j < 4; ++j) { d[j] = vv[j] - mean; s2 += d[j] * d[j]; }
    __syncthreads();
#pragma unroll
    for (int off = 32; off; off >>= 1) s2 += __shfl_down(s2, off, 64);
    if ((tid & 63) == 0) red[tid >> 6] = s2;
    __syncthreads();
    if (tid == 0) stat = (red[0] + red[1] + red[2] + red[3]) * (1.0f / 1024.0f);
    __syncthreads();
    float inv = 1.0f / sqrtf(stat + 1e-5f);
    float4 gg = *(const float4*)&g[tid * 4];
    float4 bv = *(const float4*)&bb[tid * 4];
    float g4[4] = {gg.x, gg.y, gg.z, gg.w};
    float b4[4] = {bv.x, bv.y, bv.z, bv.w};
    float out[4];
#pragma unroll
    for (int j = 0; j < 4; ++j) out[j] = d[j] * inv * g4[j] + b4[j];
    *(float4*)&xr[tid * 4] = make_float4(out[0], out[1], out[2], out[3]);
    bf16x4 ob = {(__bf16)out[0], (__bf16)out[1], (__bf16)out[2], (__bf16)out[3]};
    *(bf16x4*)&xs_bf[row * D_ + tid * 4] = ob;
}

// ---------------- head: (8,1024) @ W_ham^T + b_ham -> (8,144) ----------------
__global__ __launch_bounds__(256) void head_kernel(
        const float* __restrict__ tgt, const float* __restrict__ W_ham,
        const float* __restrict__ b_ham, float* __restrict__ out) {
    int b = blockIdx.x;
    int tid = threadIdx.x;
    __shared__ float xr[D_];
    const float* row = tgt + ((long)b * S_ + (S_ - 1)) * D_;
    for (int i = tid; i < D_; i += 256) xr[i] = row[i];
    __syncthreads();
    for (int n = tid; n < HAM_; n += 256) {
        float acc = b_ham[n];
        const float* wr = W_ham + (long)n * D_;
        for (int kk = 0; kk < D_; ++kk) acc += xr[kk] * wr[kk];
        out[b * HAM_ + n] = acc;
    }
}

// ---------------- loss: mean((head_out - (y - w_last))^2) --------------------
__global__ __launch_bounds__(256) void loss_kernel(
        const float* __restrict__ head_out, const float* __restrict__ y,
        const float* __restrict__ w, float* __restrict__ out) {
    int tid = threadIdx.x;
    float acc = 0.0f;
    for (int i = tid; i < B_ * HAM_; i += 256) {
        int b = i / HAM_, r = i % HAM_;
        float w_last = w[((long)b * 16 + 15) * HAM_ + r];
        float resid = y[i] - w_last;
        float dd = head_out[i] - resid;
        acc += dd * dd;
    }
    __shared__ float red[4];
#pragma unroll
    for (int off = 32; off; off >>= 1) acc += __shfl_down(acc, off, 64);
    if ((tid & 63) == 0) red[tid >> 6] = acc;
    __syncthreads();
    if (tid == 0)
        out[0] = (red[0] + red[1] + red[2] + red[3]) * (1.0f / (B_ * HAM_));
}

// ---------------------------------------------------------------------------
extern "C" void kernel_launch(void* const* d_in, const int* in_sizes, int n_in,
                              void* d_out, int out_size, void* d_ws, size_t ws_size,
                              hipStream_t stream) {
    const float* x      = (const float*)d_in[0];
    const float* w      = (const float*)d_in[1];
    const float* y      = (const float*)d_in[2];
    const float* W_nail = (const float*)d_in[3];
    const float* b_nail = (const float*)d_in[4];
    const float* W_cond = (const float*)d_in[5];
    const float* b_cond = (const float*)d_in[6];
    const float* Wqkv   = (const float*)d_in[7];
    const float* bqkv   = (const float*)d_in[8];
    const float* Wo     = (const float*)d_in[9];
    const float* bo     = (const float*)d_in[10];
    const float* ln1_g  = (const float*)d_in[11];
    const float* ln1_b  = (const float*)d_in[12];
    const float* ln2_g  = (const float*)d_in[13];
    const float* ln2_b  = (const float*)d_in[14];
    const float* W1     = (const float*)d_in[15];
    const float* b1     = (const float*)d_in[16];
    const float* W2     = (const float*)d_in[17];
    const float* b2     = (const float*)d_in[18];
    const float* W_ham  = (const float*)d_in[19];
    const float* b_ham  = (const float*)d_in[20];

    float* ws = (float*)d_ws;
    const long SEG = (long)B_ * S_ * D_;            // 7,340,032 floats
    float*  tgt    = ws;                            // [0, SEG)
    float*  tmp    = ws + SEG;                      // [SEG, 2SEG)
    __bf16* tgt_bf = (__bf16*)(ws + 2 * SEG);       // [2SEG, 2.5SEG)
    __bf16* ctx_bf = (__bf16*)(ws + 2 * SEG + SEG / 2);      // [2.5SEG, 3SEG)
    __bf16* qb     = (__bf16*)(ws + 3 * SEG);                // [3SEG, 3.5SEG)
    __bf16* kb     = (__bf16*)(ws + 3 * SEG + SEG / 2);      // [3.5SEG, 4SEG)
    __bf16* vb     = (__bf16*)(ws + 4 * SEG);                // [4SEG, 4.5SEG)
    __bf16* ffh_bf = (__bf16*)(ws + 2 * SEG + SEG / 2);      // overlays ctx|q|k|v
    __bf16* wbf    = (__bf16*)(ws + 4 * SEG + SEG / 2);      // 12.58M bf16
    int*    xmask    = (int*)(ws + 4 * SEG + SEG / 2 + 6291456);
    float*  head_out = ws + 4 * SEG + SEG / 2 + 6291456 + 4096;

    __bf16* wqkv_bf = wbf;
    __bf16* wo_bf   = wbf + 3145728;
    __bf16* w1_bf   = wbf + 4194304;
    __bf16* w2_bf   = wbf + 8388608;

    const int M = B_ * S_;                          // 7168

    embed_x_kernel<<<B_ * LX_, 256, 0, stream>>>(x, W_nail, b_nail, tgt, tgt_bf, xmask);
    embed_w_kernel<<<B_ * NW_, 256, 0, stream>>>(w, W_cond, b_cond, tgt, tgt_bf);

    for (int L = 0; L < 4; ++L) {
        const int NQ = 3 * D_ * D_, NO = D_ * D_, N1 = FF_ * D_, N2 = D_ * FF_;
        convert4_kernel<<<12288, 256, 0, stream>>>(
            Wqkv + (size_t)L * NQ, Wo + (size_t)L * NO,
            W1 + (size_t)L * N1, W2 + (size_t)L * N2,
            wqkv_bf, wo_bf, w1_bf, w2_bf);

        gemm_mfma<2><<<dim3(3 * D_ / 128, M / 128), 256, 0, stream>>>(
            tgt_bf, wqkv_bf, bqkv + (size_t)L * 3 * D_,
            nullptr, nullptr, qb, kb, vb, M, 3 * D_, D_);
        attn_mfma<<<B_ * H_ * (S_ / 64), 256, 0, stream>>>(qb, kb, vb, xmask, ctx_bf);
        gemm_mfma<0><<<dim3(D_ / 128, M / 128), 256, 0, stream>>>(
            ctx_bf, wo_bf, bo + (size_t)L * D_,
            tmp, nullptr, nullptr, nullptr, nullptr, M, D_, D_);
        add_ln_kernel<<<M, 256, 0, stream>>>(tgt, tgt_bf, tmp,
            ln1_g + (size_t)L * D_, ln1_b + (size_t)L * D_);
        gemm_mfma<1><<<dim3(FF_ / 128, M / 128), 256, 0, stream>>>(
            tgt_bf, w1_bf, b1 + (size_t)L * FF_,
            nullptr, ffh_bf, nullptr, nullptr, nullptr, M, FF_, D_);
        gemm_mfma<0><<<dim3(D_ / 128, M / 128), 256, 0, stream>>>(
            ffh_bf, w2_bf, b2 + (size_t)L * D_,
            tmp, nullptr, nullptr, nullptr, nullptr, M, D_, FF_);
        add_ln_kernel<<<M, 256, 0, stream>>>(tgt, tgt_bf, tmp,
            ln2_g + (size_t)L * D_, ln2_b + (size_t)L * D_);
    }

    head_kernel<<<B_, 256, 0, stream>>>(tgt, W_ham, b_ham, head_out);
    loss_kernel<<<1, 256, 0, stream>>>(head_out, y, w, (float*)d_out);
}

// Round 5
// 1931.074 us; speedup vs baseline: 5.9355x; 1.1186x over previous
//
#include <hip/hip_runtime.h>
#include <math.h>

// ---------------------------------------------------------------------------
// TransformerContinuous: B=8, Lx=512, n_w=384, S=896, D=1024, H=16, hd=64,
// NL=4, FF=4096, HAM=144.
// Round 5: GEMM K-loop BK=64 (half the barrier drains), XOR-swizzled LDS
// (kills 8-way ds_read bank conflicts), bf16 tmp stream.
// ---------------------------------------------------------------------------

#define B_      8
#define LX_     512
#define NW_     384
#define S_      896
#define D_      1024
#define H_      16
#define HD_     64
#define FF_     4096
#define HAM_    144

#define RMS_SCALE 0.9999500037496876f            // 1/sqrt(1.0001)
#define PE_C     (-6.907755278982137f / 1024.0f) // -ln(1000)/D

typedef __bf16 bf16x4 __attribute__((ext_vector_type(4)));
typedef __bf16 bf16x8 __attribute__((ext_vector_type(8)));
typedef float  f32x4  __attribute__((ext_vector_type(4)));

static __device__ __forceinline__ float nan0(float v) { return (v != v) ? 0.0f : v; }

static __device__ __forceinline__ void async_copy16(const __bf16* g, __bf16* l) {
    __builtin_amdgcn_global_load_lds(
        (const __attribute__((address_space(1))) void*)g,
        (__attribute__((address_space(3))) void*)l, 16, 0, 0);
}

// tanh-form GELU, one v_exp_f32; |err| vs exact-erf GELU < ~3e-4 (sub-bf16-ulp)
static __device__ __forceinline__ float fast_gelu(float x) {
    float x3 = x * x * x;
    float z = 0.7978845608028654f * x + 0.035677408136300125f * x3;
    float az = fabsf(z);
    float e = __expf(2.0f * az);
    float t = 1.0f - 2.0f / (e + 1.0f);
    t = (z < 0.0f) ? -t : t;
    return 0.5f * x * (1.0f + t);
}

// ---------------- fused fp32 -> bf16 conversion of 4 weight tensors ---------
__global__ __launch_bounds__(256) void convert4_kernel(
        const float* __restrict__ s0, const float* __restrict__ s1,
        const float* __restrict__ s2, const float* __restrict__ s3,
        __bf16* __restrict__ d0, __bf16* __restrict__ d1,
        __bf16* __restrict__ d2, __bf16* __restrict__ d3) {
    int blk = blockIdx.x;
    const float* src; __bf16* dst; int base;
    if (blk < 3072)      { src = s0; dst = d0; base = blk; }
    else if (blk < 4096) { src = s1; dst = d1; base = blk - 3072; }
    else if (blk < 8192) { src = s2; dst = d2; base = blk - 4096; }
    else                 { src = s3; dst = d3; base = blk - 8192; }
    int i = (base * 256 + threadIdx.x) * 4;
    float4 v = *(const float4*)&src[i];
    bf16x4 o = {(__bf16)v.x, (__bf16)v.y, (__bf16)v.z, (__bf16)v.w};
    *(bf16x4*)&dst[i] = o;
}

// ---------------- embed x: rows (b,i) of x -> tgt rows 0..511 ----------------
__global__ __launch_bounds__(256) void embed_x_kernel(
        const float* __restrict__ x, const float* __restrict__ W_nail,
        const float* __restrict__ b_nail, float* __restrict__ tgt,
        __bf16* __restrict__ tgt_bf, int* __restrict__ xmask) {
    int row = blockIdx.x;              // b*512 + i
    int b = row >> 9, i = row & 511;
    const float* xr = x + (long)row * 64;
    __shared__ float xn[64];
    __shared__ float t_s;
    int tid = threadIdx.x;
    if (tid < 64) {
        float vv = xr[tid];
        float v0 = nan0(vv);
        xn[tid] = fminf(fmaxf(v0 * RMS_SCALE, -5.0f), 5.0f);
        if (tid == 0) { t_s = v0; xmask[row] = (vv != vv) ? 1 : 0; }
    }
    __syncthreads();
    float t = t_s;
    int d0 = tid * 4;
    float acc[4];
#pragma unroll
    for (int j = 0; j < 4; ++j) acc[j] = b_nail[d0 + j];
    const float* w0 = W_nail + (long)d0 * 63;
    for (int k = 0; k < 63; ++k) {
        float xv = xn[k + 1];
#pragma unroll
        for (int j = 0; j < 4; ++j) acc[j] += xv * w0[j * 63 + k];
    }
    float out[4];
#pragma unroll
    for (int j = 0; j < 4; ++j) {
        int d = d0 + j;
        float div = expf((float)(d >> 1) * PE_C);
        float ang = t * div;
        out[j] = acc[j] + ((d & 1) ? cosf(ang) : sinf(ang));
    }
    long idx = ((long)b * S_ + i) * D_ + d0;
    *(float4*)&tgt[idx] = make_float4(out[0], out[1], out[2], out[3]);
    bf16x4 ob = {(__bf16)out[0], (__bf16)out[1], (__bf16)out[2], (__bf16)out[3]};
    *(bf16x4*)&tgt_bf[idx] = ob;
}

// ---------------- embed w: rows (b,j) of w -> tgt rows 512..895 ----------------
__global__ __launch_bounds__(256) void embed_w_kernel(
        const float* __restrict__ w, const float* __restrict__ W_cond,
        const float* __restrict__ b_cond, float* __restrict__ tgt,
        __bf16* __restrict__ tgt_bf) {
    int row = blockIdx.x;              // b*384 + j
    int b = row / NW_, j = row % NW_;
    const float* wr = w + (long)row * 6;
    float wn[6];
#pragma unroll
    for (int k = 0; k < 6; ++k)
        wn[k] = fminf(fmaxf(nan0(wr[k]) * RMS_SCALE, -5.0f), 5.0f);
    int tid = threadIdx.x;
    int d0 = tid * 4;
    float pos = (float)(LX_ + j);
    float out[4];
#pragma unroll
    for (int jj = 0; jj < 4; ++jj) {
        int d = d0 + jj;
        float acc = b_cond[d];
        const float* wc = W_cond + (long)d * 6;
#pragma unroll
        for (int k = 0; k < 6; ++k) acc += wn[k] * wc[k];
        float div = expf((float)(d >> 1) * PE_C);
        float ang = pos * div;
        out[jj] = acc + ((d & 1) ? cosf(ang) : sinf(ang));
    }
    long idx = ((long)b * S_ + LX_ + j) * D_ + d0;
    *(float4*)&tgt[idx] = make_float4(out[0], out[1], out[2], out[3]);
    bf16x4 ob = {(__bf16)out[0], (__bf16)out[1], (__bf16)out[2], (__bf16)out[3]};
    *(bf16x4*)&tgt_bf[idx] = ob;
}

// ---------------- bf16 MFMA GEMM: C[M,N] = A[M,K] @ W[N,K]^T + bias ---------
// 128x128 tile, BK=64, 4 waves each computing 64x64 via 2x(4x4) 16x16x32 MFMAs.
// LDS XOR swizzle: chunk c (16B) of row r stored at slot c^(r&7) -> ds_read
// bank aliasing is 2-way (free).  MFMA operands swapped: lane holds 4
// consecutive n-cols per acc -> vectorized stores.
// MODE 0: bf16 out + bias   MODE 1: bf16 out + bias + fast GELU
// MODE 2: bf16 out + bias, split to q/k/v (B,H,S,64)
template <int MODE>
__global__ __launch_bounds__(256) void gemm_mfma(
        const __bf16* __restrict__ A, const __bf16* __restrict__ W,
        const float* __restrict__ bias,
        __bf16* __restrict__ Cb,
        __bf16* __restrict__ Cq, __bf16* __restrict__ Ck, __bf16* __restrict__ Cv,
        int M, int N, int K) {
    __shared__ __bf16 As[128 * 64];    // 16 KB
    __shared__ __bf16 Bs[128 * 64];    // 16 KB
    int tid = threadIdx.x;
    int wave = tid >> 6, lane = tid & 63;
    int m0 = blockIdx.y * 128, n0 = blockIdx.x * 128;
    int wm = (wave >> 1) * 64, wn = (wave & 1) * 64;

    // staging: each wave stages 32 rows x 64 cols of A and of B per iter.
    // lane's LDS slot (row=lane>>3, chunk=lane&7); global chunk swizzled.
    int srow = wave * 32 + (lane >> 3);
    int scol = ((lane & 7) ^ (lane >> 3)) * 8;
    const __bf16* Ag = A + (size_t)(m0 + srow) * K + scol;
    const __bf16* Wg = W + (size_t)(n0 + srow) * K + scol;
    __bf16* Al = &As[wave * 2048];
    __bf16* Bl = &Bs[wave * 2048];

    f32x4 acc[4][4];
#pragma unroll
    for (int i = 0; i < 4; ++i)
#pragma unroll
        for (int j = 0; j < 4; ++j) acc[i][j] = 0.0f;

    int frow = lane & 15;
    int quad = lane >> 4;
    int sf = frow & 7;                 // row-swizzle term (period 8)

    for (int k0 = 0; k0 < K; k0 += 64) {
        size_t off = (size_t)k0;
        async_copy16(Ag + off,                  Al);
        async_copy16(Ag + off + (size_t)8 * K,  Al + 512);
        async_copy16(Ag + off + (size_t)16 * K, Al + 1024);
        async_copy16(Ag + off + (size_t)24 * K, Al + 1536);
        async_copy16(Wg + off,                  Bl);
        async_copy16(Wg + off + (size_t)8 * K,  Bl + 512);
        async_copy16(Wg + off + (size_t)16 * K, Bl + 1024);
        async_copy16(Wg + off + (size_t)24 * K, Bl + 1536);
        __syncthreads();
#pragma unroll
        for (int ks = 0; ks < 2; ++ks) {
            int slot = ((quad + ks * 4) ^ sf) * 8;
            bf16x8 a[4], b[4];
#pragma unroll
            for (int mi = 0; mi < 4; ++mi)
                a[mi] = *(const bf16x8*)&As[(wm + mi * 16 + frow) * 64 + slot];
#pragma unroll
            for (int ni = 0; ni < 4; ++ni)
                b[ni] = *(const bf16x8*)&Bs[(wn + ni * 16 + frow) * 64 + slot];
#pragma unroll
            for (int mi = 0; mi < 4; ++mi)
#pragma unroll
                for (int ni = 0; ni < 4; ++ni)
                    acc[mi][ni] = __builtin_amdgcn_mfma_f32_16x16x32_bf16(
                        b[ni], a[mi], acc[mi][ni], 0, 0, 0);
        }
        __syncthreads();
    }

    // epilogue (swapped layout): m = lane&15, n = quad*4 + r
    int mrow_l = lane & 15;
    int nq = (lane >> 4) * 4;
#pragma unroll
    for (int ni = 0; ni < 4; ++ni) {
        int cg0 = n0 + wn + ni * 16 + nq;
        float4 bv = *(const float4*)&bias[cg0];
        float bz[4] = {bv.x, bv.y, bv.z, bv.w};
#pragma unroll
        for (int mi = 0; mi < 4; ++mi) {
            int rg = m0 + wm + mi * 16 + mrow_l;
            float vv[4];
#pragma unroll
            for (int r = 0; r < 4; ++r) {
                float v = acc[mi][ni][r] + bz[r];
                if (MODE == 1) v = fast_gelu(v);
                vv[r] = v;
            }
            bf16x4 o = {(__bf16)vv[0], (__bf16)vv[1], (__bf16)vv[2], (__bf16)vv[3]};
            if (MODE == 2) {
                int which = cg0 >> 10;        // 0=q 1=k 2=v
                int h = (cg0 & 1023) >> 6;
                int e = cg0 & 63;
                int bb = rg / S_, s = rg % S_;
                __bf16* dst = (which == 0) ? Cq : (which == 1) ? Ck : Cv;
                *(bf16x4*)&dst[(((size_t)bb * H_ + h) * S_ + s) * HD_ + e] = o;
            } else {
                *(bf16x4*)&Cb[(size_t)rg * N + cg0] = o;
            }
        }
    }
}

// ---------------- MFMA flash attention (bf16 in, bf16 ctx out) --------------
__global__ __launch_bounds__(256) void attn_mfma(
        const __bf16* __restrict__ q, const __bf16* __restrict__ k,
        const __bf16* __restrict__ v, const int* __restrict__ xmask,
        __bf16* __restrict__ ctx) {
    __shared__ __bf16 Ks[64][72];
    __shared__ __bf16 Vt[64][66];       // Vt[d][k]
    __shared__ __bf16 Ps[4][16][72];    // per-wave P in A-layout
    __shared__ float mb[LX_];           // x-mask bias: 0 or -inf
    int tid = threadIdx.x;
    int wave = tid >> 6, lane = tid & 63;
    int frow = lane & 15, quad = lane >> 4;
    int blk = blockIdx.x;
    int qt = blk % 14;
    int bh = blk / 14;
    int b = bh >> 4, h = bh & 15;
    int q0 = qt * 64;
    int q0w = q0 + wave * 16;
    size_t base = (size_t)bh * S_ * HD_;

    for (int i = tid; i < LX_; i += 256)
        mb[i] = xmask[(b << 9) + i] ? -INFINITY : 0.0f;

    const __bf16* qrow = q + base + (size_t)(q0w + frow) * HD_ + quad * 8;
    bf16x8 aq0 = *(const bf16x8*)qrow;
    bf16x8 aq1 = *(const bf16x8*)(qrow + 32);

    f32x4 o[4];
#pragma unroll
    for (int dt = 0; dt < 4; ++dt) o[dt] = 0.0f;
    float mrow[4] = {-INFINITY, -INFINITY, -INFINITY, -INFINITY};
    float lrow[4] = {0.0f, 0.0f, 0.0f, 0.0f};

    int kend = (q0 >= LX_) ? (q0 + 64) : LX_;

    int sr = tid >> 2;
    int sc = (tid & 3) * 8;
    const __bf16* kg = k + base + (size_t)sr * HD_ + sc;
    const __bf16* vg = v + base + (size_t)sr * HD_ + sc;

    for (int k0 = 0; k0 < kend; k0 += 64) {
        {
            size_t off = (size_t)k0 * HD_;
            bf16x8 k0v = *(const bf16x8*)(kg + off);
            bf16x8 k1v = *(const bf16x8*)(kg + off + 32);
            *(bf16x8*)&Ks[sr][sc] = k0v;
            *(bf16x8*)&Ks[sr][sc + 32] = k1v;
            bf16x8 v0v = *(const bf16x8*)(vg + off);
            bf16x8 v1v = *(const bf16x8*)(vg + off + 32);
#pragma unroll
            for (int j = 0; j < 8; ++j) {
                Vt[sc + j][sr] = v0v[j];
                Vt[sc + 32 + j][sr] = v1v[j];
            }
        }
        __syncthreads();

        f32x4 scr[4];
#pragma unroll
        for (int nt = 0; nt < 4; ++nt) {
            bf16x8 bk0 = *(const bf16x8*)&Ks[nt * 16 + frow][quad * 8];
            bf16x8 bk1 = *(const bf16x8*)&Ks[nt * 16 + frow][32 + quad * 8];
            f32x4 z = 0.0f;
            z = __builtin_amdgcn_mfma_f32_16x16x32_bf16(aq0, bk0, z, 0, 0, 0);
            z = __builtin_amdgcn_mfma_f32_16x16x32_bf16(aq1, bk1, z, 0, 0, 0);
            scr[nt] = z;
        }

        float tmax[4] = {-INFINITY, -INFINITY, -INFINITY, -INFINITY};
#pragma unroll
        for (int nt = 0; nt < 4; ++nt) {
            int kj = k0 + nt * 16 + frow;
            float bias = (kj < LX_) ? mb[kj] : 0.0f;
#pragma unroll
            for (int r = 0; r < 4; ++r) {
                float s = scr[nt][r] * 0.125f + bias;
                if (kj >= LX_ && kj > q0w + quad * 4 + r) s = -INFINITY;
                scr[nt][r] = s;
                tmax[r] = fmaxf(tmax[r], s);
            }
        }
#pragma unroll
        for (int off = 1; off < 16; off <<= 1)
#pragma unroll
            for (int r = 0; r < 4; ++r)
                tmax[r] = fmaxf(tmax[r], __shfl_xor(tmax[r], off, 64));

        float alpha[4], rsum[4];
#pragma unroll
        for (int r = 0; r < 4; ++r) {
            float nm = fmaxf(mrow[r], tmax[r]);
            alpha[r] = (nm == -INFINITY) ? 1.0f : __expf(mrow[r] - nm);
            mrow[r] = nm;
            rsum[r] = 0.0f;
        }
#pragma unroll
        for (int nt = 0; nt < 4; ++nt) {
#pragma unroll
            for (int r = 0; r < 4; ++r) {
                float s = scr[nt][r];
                float p = (s == -INFINITY) ? 0.0f : __expf(s - mrow[r]);
                rsum[r] += p;
                Ps[wave][quad * 4 + r][nt * 16 + frow] = (__bf16)p;
            }
        }
#pragma unroll
        for (int off = 1; off < 16; off <<= 1)
#pragma unroll
            for (int r = 0; r < 4; ++r)
                rsum[r] += __shfl_xor(rsum[r], off, 64);
#pragma unroll
        for (int r = 0; r < 4; ++r)
            lrow[r] = lrow[r] * alpha[r] + rsum[r];
#pragma unroll
        for (int dt = 0; dt < 4; ++dt)
#pragma unroll
            for (int r = 0; r < 4; ++r)
                o[dt][r] *= alpha[r];

        bf16x8 ap0 = *(const bf16x8*)&Ps[wave][frow][quad * 8];
        bf16x8 ap1 = *(const bf16x8*)&Ps[wave][frow][32 + quad * 8];
#pragma unroll
        for (int dt = 0; dt < 4; ++dt) {
            bf16x8 bv0 = *(const bf16x8*)&Vt[dt * 16 + frow][quad * 8];
            bf16x8 bv1 = *(const bf16x8*)&Vt[dt * 16 + frow][32 + quad * 8];
            o[dt] = __builtin_amdgcn_mfma_f32_16x16x32_bf16(ap0, bv0, o[dt], 0, 0, 0);
            o[dt] = __builtin_amdgcn_mfma_f32_16x16x32_bf16(ap1, bv1, o[dt], 0, 0, 0);
        }
        __syncthreads();
    }

#pragma unroll
    for (int r = 0; r < 4; ++r) {
        float inv = (lrow[r] > 0.0f) ? 1.0f / lrow[r] : 0.0f;
        int qg = q0w + quad * 4 + r;
        size_t ob = ((size_t)b * S_ + qg) * D_ + h * HD_;
#pragma unroll
        for (int dt = 0; dt < 4; ++dt)
            ctx[ob + dt * 16 + frow] = (__bf16)(o[dt][r] * inv);
    }
}

// ---------------- fused residual add + LayerNorm (bf16 o input) -------------
__global__ __launch_bounds__(256) void add_ln_kernel(
        float* __restrict__ xs, __bf16* __restrict__ xs_bf,
        const __bf16* __restrict__ o,
        const float* __restrict__ g, const float* __restrict__ bb) {
    long row = blockIdx.x;
    float* xr = xs + row * D_;
    const __bf16* orr = o + row * D_;
    int tid = threadIdx.x;
    float4 a = *(const float4*)&xr[tid * 4];
    bf16x4 b4v = *(const bf16x4*)&orr[tid * 4];
    float vv[4] = {a.x + (float)b4v[0], a.y + (float)b4v[1],
                   a.z + (float)b4v[2], a.w + (float)b4v[3]};
    float s = vv[0] + vv[1] + vv[2] + vv[3];
    __shared__ float red[4];
    __shared__ float stat;
#pragma unroll
    for (int off = 32; off; off >>= 1) s += __shfl_down(s, off, 64);
    if ((tid & 63) == 0) red[tid >> 6] = s;
    __syncthreads();
    if (tid == 0) stat = (red[0] + red[1] + red[2] + red[3]) * (1.0f / 1024.0f);
    __syncthreads();
    float mean = stat;
    float d[4];
    float s2 = 0.0f;
#pragma unroll
    for (int j = 0; j < 4; ++j) { d[j] = vv[j] - mean; s2 += d[j] * d[j]; }
    __syncthreads();
#pragma unroll
    for (int off = 32; off; off >>= 1) s2 += __shfl_down(s2, off, 64);
    if ((tid & 63) == 0) red[tid >> 6] = s2;
    __syncthreads();
    if (tid == 0) stat = (red[0] + red[1] + red[2] + red[3]) * (1.0f / 1024.0f);
    __syncthreads();
    float inv = 1.0f / sqrtf(stat + 1e-5f);
    float4 gg = *(const float4*)&g[tid * 4];
    float4 bv = *(const float4*)&bb[tid * 4];
    float g4[4] = {gg.x, gg.y, gg.z, gg.w};
    float b4[4] = {bv.x, bv.y, bv.z, bv.w};
    float out[4];
#pragma unroll
    for (int j = 0; j < 4; ++j) out[j] = d[j] * inv * g4[j] + b4[j];
    *(float4*)&xr[tid * 4] = make_float4(out[0], out[1], out[2], out[3]);
    bf16x4 ob = {(__bf16)out[0], (__bf16)out[1], (__bf16)out[2], (__bf16)out[3]};
    *(bf16x4*)&xs_bf[row * D_ + tid * 4] = ob;
}

// ---------------- head: (8,1024) @ W_ham^T + b_ham -> (8,144) ----------------
__global__ __launch_bounds__(256) void head_kernel(
        const float* __restrict__ tgt, const float* __restrict__ W_ham,
        const float* __restrict__ b_ham, float* __restrict__ out) {
    int b = blockIdx.x;
    int tid = threadIdx.x;
    __shared__ float xr[D_];
    const float* row = tgt + ((long)b * S_ + (S_ - 1)) * D_;
    for (int i = tid; i < D_; i += 256) xr[i] = row[i];
    __syncthreads();
    for (int n = tid; n < HAM_; n += 256) {
        float acc = b_ham[n];
        const float* wr = W_ham + (long)n * D_;
        for (int kk = 0; kk < D_; ++kk) acc += xr[kk] * wr[kk];
        out[b * HAM_ + n] = acc;
    }
}

// ---------------- loss: mean((head_out - (y - w_last))^2) --------------------
__global__ __launch_bounds__(256) void loss_kernel(
        const float* __restrict__ head_out, const float* __restrict__ y,
        const float* __restrict__ w, float* __restrict__ out) {
    int tid = threadIdx.x;
    float acc = 0.0f;
    for (int i = tid; i < B_ * HAM_; i += 256) {
        int b = i / HAM_, r = i % HAM_;
        float w_last = w[((long)b * 16 + 15) * HAM_ + r];
        float resid = y[i] - w_last;
        float dd = head_out[i] - resid;
        acc += dd * dd;
    }
    __shared__ float red[4];
#pragma unroll
    for (int off = 32; off; off >>= 1) acc += __shfl_down(acc, off, 64);
    if ((tid & 63) == 0) red[tid >> 6] = acc;
    __syncthreads();
    if (tid == 0)
        out[0] = (red[0] + red[1] + red[2] + red[3]) * (1.0f / (B_ * HAM_));
}

// ---------------------------------------------------------------------------
extern "C" void kernel_launch(void* const* d_in, const int* in_sizes, int n_in,
                              void* d_out, int out_size, void* d_ws, size_t ws_size,
                              hipStream_t stream) {
    const float* x      = (const float*)d_in[0];
    const float* w      = (const float*)d_in[1];
    const float* y      = (const float*)d_in[2];
    const float* W_nail = (const float*)d_in[3];
    const float* b_nail = (const float*)d_in[4];
    const float* W_cond = (const float*)d_in[5];
    const float* b_cond = (const float*)d_in[6];
    const float* Wqkv   = (const float*)d_in[7];
    const float* bqkv   = (const float*)d_in[8];
    const float* Wo     = (const float*)d_in[9];
    const float* bo     = (const float*)d_in[10];
    const float* ln1_g  = (const float*)d_in[11];
    const float* ln1_b  = (const float*)d_in[12];
    const float* ln2_g  = (const float*)d_in[13];
    const float* ln2_b  = (const float*)d_in[14];
    const float* W1     = (const float*)d_in[15];
    const float* b1     = (const float*)d_in[16];
    const float* W2     = (const float*)d_in[17];
    const float* b2     = (const float*)d_in[18];
    const float* W_ham  = (const float*)d_in[19];
    const float* b_ham  = (const float*)d_in[20];

    float* ws = (float*)d_ws;
    const long SEG = (long)B_ * S_ * D_;            // 7,340,032 floats
    float*  tgt    = ws;                            // [0, SEG)
    __bf16* tmp_bf = (__bf16*)(ws + SEG);           // [SEG, 1.5SEG)
    __bf16* tgt_bf = (__bf16*)(ws + 2 * SEG);       // [2SEG, 2.5SEG)
    __bf16* ctx_bf = (__bf16*)(ws + 2 * SEG + SEG / 2);      // [2.5SEG, 3SEG)
    __bf16* qb     = (__bf16*)(ws + 3 * SEG);                // [3SEG, 3.5SEG)
    __bf16* kb     = (__bf16*)(ws + 3 * SEG + SEG / 2);      // [3.5SEG, 4SEG)
    __bf16* vb     = (__bf16*)(ws + 4 * SEG);                // [4SEG, 4.5SEG)
    __bf16* ffh_bf = (__bf16*)(ws + 2 * SEG + SEG / 2);      // overlays ctx|q|k|v
    __bf16* wbf    = (__bf16*)(ws + 4 * SEG + SEG / 2);      // 12.58M bf16
    int*    xmask    = (int*)(ws + 4 * SEG + SEG / 2 + 6291456);
    float*  head_out = ws + 4 * SEG + SEG / 2 + 6291456 + 4096;

    __bf16* wqkv_bf = wbf;
    __bf16* wo_bf   = wbf + 3145728;
    __bf16* w1_bf   = wbf + 4194304;
    __bf16* w2_bf   = wbf + 8388608;

    const int M = B_ * S_;                          // 7168

    embed_x_kernel<<<B_ * LX_, 256, 0, stream>>>(x, W_nail, b_nail, tgt, tgt_bf, xmask);
    embed_w_kernel<<<B_ * NW_, 256, 0, stream>>>(w, W_cond, b_cond, tgt, tgt_bf);

    for (int L = 0; L < 4; ++L) {
        const int NQ = 3 * D_ * D_, NO = D_ * D_, N1 = FF_ * D_, N2 = D_ * FF_;
        convert4_kernel<<<12288, 256, 0, stream>>>(
            Wqkv + (size_t)L * NQ, Wo + (size_t)L * NO,
            W1 + (size_t)L * N1, W2 + (size_t)L * N2,
            wqkv_bf, wo_bf, w1_bf, w2_bf);

        gemm_mfma<2><<<dim3(3 * D_ / 128, M / 128), 256, 0, stream>>>(
            tgt_bf, wqkv_bf, bqkv + (size_t)L * 3 * D_,
            nullptr, qb, kb, vb, M, 3 * D_, D_);
        attn_mfma<<<B_ * H_ * (S_ / 64), 256, 0, stream>>>(qb, kb, vb, xmask, ctx_bf);
        gemm_mfma<0><<<dim3(D_ / 128, M / 128), 256, 0, stream>>>(
            ctx_bf, wo_bf, bo + (size_t)L * D_,
            tmp_bf, nullptr, nullptr, nullptr, M, D_, D_);
        add_ln_kernel<<<M, 256, 0, stream>>>(tgt, tgt_bf, tmp_bf,
            ln1_g + (size_t)L * D_, ln1_b + (size_t)L * D_);
        gemm_mfma<1><<<dim3(FF_ / 128, M / 128), 256, 0, stream>>>(
            tgt_bf, w1_bf, b1 + (size_t)L * FF_,
            ffh_bf, nullptr, nullptr, nullptr, M, FF_, D_);
        gemm_mfma<0><<<dim3(D_ / 128, M / 128), 256, 0, stream>>>(
            ffh_bf, w2_bf, b2 + (size_t)L * D_,
            tmp_bf, nullptr, nullptr, nullptr, M, D_, FF_);
        add_ln_kernel<<<M, 256, 0, stream>>>(tgt, tgt_bf, tmp_bf,
            ln2_g + (size_t)L * D_, ln2_b + (size_t)L * D_);
    }

    head_kernel<<<B_, 256, 0, stream>>>(tgt, W_ham, b_ham, head_out);
    loss_kernel<<<1, 256, 0, stream>>>(head_out, y, w, (float*)d_out);
}

// Round 6
// 1826.400 us; speedup vs baseline: 6.2757x; 1.0573x over previous
//
#include <hip/hip_runtime.h>
#include <math.h>

// ---------------------------------------------------------------------------
// TransformerContinuous: B=8, Lx=512, n_w=384, S=896, D=1024, H=16, hd=64,
// NL=4, FF=4096, HAM=144.
// Round 6: embed_x rewritten (transposed W_nail, coalesced float4, 8 rows per
// block); residual stream is bf16-only (no fp32 tgt mirror).
// ---------------------------------------------------------------------------

#define B_      8
#define LX_     512
#define NW_     384
#define S_      896
#define D_      1024
#define H_      16
#define HD_     64
#define FF_     4096
#define HAM_    144

#define RMS_SCALE 0.9999500037496876f            // 1/sqrt(1.0001)
#define PE_C     (-6.907755278982137f / 1024.0f) // -ln(1000)/D

typedef __bf16 bf16x4 __attribute__((ext_vector_type(4)));
typedef __bf16 bf16x8 __attribute__((ext_vector_type(8)));
typedef float  f32x4  __attribute__((ext_vector_type(4)));

static __device__ __forceinline__ float nan0(float v) { return (v != v) ? 0.0f : v; }

static __device__ __forceinline__ void async_copy16(const __bf16* g, __bf16* l) {
    __builtin_amdgcn_global_load_lds(
        (const __attribute__((address_space(1))) void*)g,
        (__attribute__((address_space(3))) void*)l, 16, 0, 0);
}

// tanh-form GELU, one v_exp_f32; |err| vs exact-erf GELU < ~3e-4 (sub-bf16-ulp)
static __device__ __forceinline__ float fast_gelu(float x) {
    float x3 = x * x * x;
    float z = 0.7978845608028654f * x + 0.035677408136300125f * x3;
    float az = fabsf(z);
    float e = __expf(2.0f * az);
    float t = 1.0f - 2.0f / (e + 1.0f);
    t = (z < 0.0f) ? -t : t;
    return 0.5f * x * (1.0f + t);
}

// ---------------- fused fp32 -> bf16 conversion of 4 weight tensors ---------
__global__ __launch_bounds__(256) void convert4_kernel(
        const float* __restrict__ s0, const float* __restrict__ s1,
        const float* __restrict__ s2, const float* __restrict__ s3,
        __bf16* __restrict__ d0, __bf16* __restrict__ d1,
        __bf16* __restrict__ d2, __bf16* __restrict__ d3) {
    int blk = blockIdx.x;
    const float* src; __bf16* dst; int base;
    if (blk < 3072)      { src = s0; dst = d0; base = blk; }
    else if (blk < 4096) { src = s1; dst = d1; base = blk - 3072; }
    else if (blk < 8192) { src = s2; dst = d2; base = blk - 4096; }
    else                 { src = s3; dst = d3; base = blk - 8192; }
    int i = (base * 256 + threadIdx.x) * 4;
    float4 v = *(const float4*)&src[i];
    bf16x4 o = {(__bf16)v.x, (__bf16)v.y, (__bf16)v.z, (__bf16)v.w};
    *(bf16x4*)&dst[i] = o;
}

// ---------------- transpose W_nail (1024x63) -> W_nailT (63x1024) -----------
__global__ __launch_bounds__(256) void transpose_nail_kernel(
        const float* __restrict__ W_nail, float* __restrict__ WT) {
    int i = blockIdx.x * 256 + threadIdx.x;      // 63*1024 = 64512, grid 252
    int d = i & 1023, kk = i >> 10;
    WT[kk * 1024 + d] = W_nail[d * 63 + kk];
}

// ---------------- embed x: 8 rows per block, coalesced W_nailT ---------------
__global__ __launch_bounds__(256) void embed_x_kernel(
        const float* __restrict__ x, const float* __restrict__ WT,
        const float* __restrict__ b_nail, __bf16* __restrict__ tgt_bf,
        int* __restrict__ xmask) {
    int row0 = blockIdx.x * 8;               // 8 rows of (b*512+i)
    int tid = threadIdx.x;
    __shared__ float xn[8][64];
    __shared__ float ts[8];
#pragma unroll
    for (int it = 0; it < 2; ++it) {
        int i = tid + it * 256;              // 0..511
        int r = i >> 6, c = i & 63;
        float vv = x[(size_t)(row0 + r) * 64 + c];
        float v0 = nan0(vv);
        xn[r][c] = fminf(fmaxf(v0 * RMS_SCALE, -5.0f), 5.0f);
        if (c == 0) { ts[r] = v0; xmask[row0 + r] = (vv != vv) ? 1 : 0; }
    }
    __syncthreads();
    int d0 = tid * 4;
    float4 bz = *(const float4*)&b_nail[d0];
    float acc[8][4];
#pragma unroll
    for (int r = 0; r < 8; ++r) {
        acc[r][0] = bz.x; acc[r][1] = bz.y; acc[r][2] = bz.z; acc[r][3] = bz.w;
    }
    for (int k = 0; k < 63; ++k) {
        float4 wv = *(const float4*)&WT[k * 1024 + d0];
#pragma unroll
        for (int r = 0; r < 8; ++r) {
            float xv = xn[r][k + 1];         // block-uniform -> LDS broadcast
            acc[r][0] += xv * wv.x; acc[r][1] += xv * wv.y;
            acc[r][2] += xv * wv.z; acc[r][3] += xv * wv.w;
        }
    }
    float div[4];
#pragma unroll
    for (int j = 0; j < 4; ++j)
        div[j] = __expf((float)((d0 + j) >> 1) * PE_C);
#pragma unroll
    for (int r = 0; r < 8; ++r) {
        int row = row0 + r;
        int b = row >> 9, i = row & 511;
        float t = ts[r];
        bf16x4 ob;
#pragma unroll
        for (int j = 0; j < 4; ++j) {
            float ang = t * div[j];
            float pe = ((d0 + j) & 1) ? __cosf(ang) : __sinf(ang);
            ob[j] = (__bf16)(acc[r][j] + pe);
        }
        *(bf16x4*)&tgt_bf[((size_t)b * S_ + i) * D_ + d0] = ob;
    }
}

// ---------------- embed w: rows (b,j) of w -> tgt rows 512..895 ----------------
__global__ __launch_bounds__(256) void embed_w_kernel(
        const float* __restrict__ w, const float* __restrict__ W_cond,
        const float* __restrict__ b_cond, __bf16* __restrict__ tgt_bf) {
    int row = blockIdx.x;              // b*384 + j
    int b = row / NW_, j = row % NW_;
    const float* wr = w + (long)row * 6;
    float wn[6];
#pragma unroll
    for (int k = 0; k < 6; ++k)
        wn[k] = fminf(fmaxf(nan0(wr[k]) * RMS_SCALE, -5.0f), 5.0f);
    int tid = threadIdx.x;
    int d0 = tid * 4;
    float pos = (float)(LX_ + j);
    bf16x4 ob;
#pragma unroll
    for (int jj = 0; jj < 4; ++jj) {
        int d = d0 + jj;
        float acc = b_cond[d];
        const float* wc = W_cond + (long)d * 6;
#pragma unroll
        for (int k = 0; k < 6; ++k) acc += wn[k] * wc[k];
        float dv = expf((float)(d >> 1) * PE_C);
        float ang = pos * dv;
        ob[jj] = (__bf16)(acc + ((d & 1) ? cosf(ang) : sinf(ang)));
    }
    *(bf16x4*)&tgt_bf[((long)b * S_ + LX_ + j) * D_ + d0] = ob;
}

// ---------------- bf16 MFMA GEMM: C[M,N] = A[M,K] @ W[N,K]^T + bias ---------
// 128x128 tile, BK=64, XOR-swizzled LDS, swapped MFMA operands (vector stores).
// MODE 0: bf16 out + bias   MODE 1: bf16 out + bias + fast GELU
// MODE 2: bf16 out + bias, split to q/k/v (B,H,S,64)
template <int MODE>
__global__ __launch_bounds__(256) void gemm_mfma(
        const __bf16* __restrict__ A, const __bf16* __restrict__ W,
        const float* __restrict__ bias,
        __bf16* __restrict__ Cb,
        __bf16* __restrict__ Cq, __bf16* __restrict__ Ck, __bf16* __restrict__ Cv,
        int M, int N, int K) {
    __shared__ __bf16 As[128 * 64];    // 16 KB
    __shared__ __bf16 Bs[128 * 64];    // 16 KB
    int tid = threadIdx.x;
    int wave = tid >> 6, lane = tid & 63;
    int m0 = blockIdx.y * 128, n0 = blockIdx.x * 128;
    int wm = (wave >> 1) * 64, wn = (wave & 1) * 64;

    int srow = wave * 32 + (lane >> 3);
    int scol = ((lane & 7) ^ (lane >> 3)) * 8;
    const __bf16* Ag = A + (size_t)(m0 + srow) * K + scol;
    const __bf16* Wg = W + (size_t)(n0 + srow) * K + scol;
    __bf16* Al = &As[wave * 2048];
    __bf16* Bl = &Bs[wave * 2048];

    f32x4 acc[4][4];
#pragma unroll
    for (int i = 0; i < 4; ++i)
#pragma unroll
        for (int j = 0; j < 4; ++j) acc[i][j] = 0.0f;

    int frow = lane & 15;
    int quad = lane >> 4;
    int sf = frow & 7;

    for (int k0 = 0; k0 < K; k0 += 64) {
        size_t off = (size_t)k0;
        async_copy16(Ag + off,                  Al);
        async_copy16(Ag + off + (size_t)8 * K,  Al + 512);
        async_copy16(Ag + off + (size_t)16 * K, Al + 1024);
        async_copy16(Ag + off + (size_t)24 * K, Al + 1536);
        async_copy16(Wg + off,                  Bl);
        async_copy16(Wg + off + (size_t)8 * K,  Bl + 512);
        async_copy16(Wg + off + (size_t)16 * K, Bl + 1024);
        async_copy16(Wg + off + (size_t)24 * K, Bl + 1536);
        __syncthreads();
#pragma unroll
        for (int ks = 0; ks < 2; ++ks) {
            int slot = ((quad + ks * 4) ^ sf) * 8;
            bf16x8 a[4], b[4];
#pragma unroll
            for (int mi = 0; mi < 4; ++mi)
                a[mi] = *(const bf16x8*)&As[(wm + mi * 16 + frow) * 64 + slot];
#pragma unroll
            for (int ni = 0; ni < 4; ++ni)
                b[ni] = *(const bf16x8*)&Bs[(wn + ni * 16 + frow) * 64 + slot];
#pragma unroll
            for (int mi = 0; mi < 4; ++mi)
#pragma unroll
                for (int ni = 0; ni < 4; ++ni)
                    acc[mi][ni] = __builtin_amdgcn_mfma_f32_16x16x32_bf16(
                        b[ni], a[mi], acc[mi][ni], 0, 0, 0);
        }
        __syncthreads();
    }

    int mrow_l = lane & 15;
    int nq = (lane >> 4) * 4;
#pragma unroll
    for (int ni = 0; ni < 4; ++ni) {
        int cg0 = n0 + wn + ni * 16 + nq;
        float4 bv = *(const float4*)&bias[cg0];
        float bz[4] = {bv.x, bv.y, bv.z, bv.w};
#pragma unroll
        for (int mi = 0; mi < 4; ++mi) {
            int rg = m0 + wm + mi * 16 + mrow_l;
            float vv[4];
#pragma unroll
            for (int r = 0; r < 4; ++r) {
                float v = acc[mi][ni][r] + bz[r];
                if (MODE == 1) v = fast_gelu(v);
                vv[r] = v;
            }
            bf16x4 o = {(__bf16)vv[0], (__bf16)vv[1], (__bf16)vv[2], (__bf16)vv[3]};
            if (MODE == 2) {
                int which = cg0 >> 10;        // 0=q 1=k 2=v
                int h = (cg0 & 1023) >> 6;
                int e = cg0 & 63;
                int bb = rg / S_, s = rg % S_;
                __bf16* dst = (which == 0) ? Cq : (which == 1) ? Ck : Cv;
                *(bf16x4*)&dst[(((size_t)bb * H_ + h) * S_ + s) * HD_ + e] = o;
            } else {
                *(bf16x4*)&Cb[(size_t)rg * N + cg0] = o;
            }
        }
    }
}

// ---------------- MFMA flash attention (bf16 in, bf16 ctx out) --------------
__global__ __launch_bounds__(256) void attn_mfma(
        const __bf16* __restrict__ q, const __bf16* __restrict__ k,
        const __bf16* __restrict__ v, const int* __restrict__ xmask,
        __bf16* __restrict__ ctx) {
    __shared__ __bf16 Ks[64][72];
    __shared__ __bf16 Vt[64][66];       // Vt[d][k]
    __shared__ __bf16 Ps[4][16][72];    // per-wave P in A-layout
    __shared__ float mb[LX_];           // x-mask bias: 0 or -inf
    int tid = threadIdx.x;
    int wave = tid >> 6, lane = tid & 63;
    int frow = lane & 15, quad = lane >> 4;
    int blk = blockIdx.x;
    int qt = blk % 14;
    int bh = blk / 14;
    int b = bh >> 4, h = bh & 15;
    int q0 = qt * 64;
    int q0w = q0 + wave * 16;
    size_t base = (size_t)bh * S_ * HD_;

    for (int i = tid; i < LX_; i += 256)
        mb[i] = xmask[(b << 9) + i] ? -INFINITY : 0.0f;

    const __bf16* qrow = q + base + (size_t)(q0w + frow) * HD_ + quad * 8;
    bf16x8 aq0 = *(const bf16x8*)qrow;
    bf16x8 aq1 = *(const bf16x8*)(qrow + 32);

    f32x4 o[4];
#pragma unroll
    for (int dt = 0; dt < 4; ++dt) o[dt] = 0.0f;
    float mrow[4] = {-INFINITY, -INFINITY, -INFINITY, -INFINITY};
    float lrow[4] = {0.0f, 0.0f, 0.0f, 0.0f};

    int kend = (q0 >= LX_) ? (q0 + 64) : LX_;

    int sr = tid >> 2;
    int sc = (tid & 3) * 8;
    const __bf16* kg = k + base + (size_t)sr * HD_ + sc;
    const __bf16* vg = v + base + (size_t)sr * HD_ + sc;

    for (int k0 = 0; k0 < kend; k0 += 64) {
        {
            size_t off = (size_t)k0 * HD_;
            bf16x8 k0v = *(const bf16x8*)(kg + off);
            bf16x8 k1v = *(const bf16x8*)(kg + off + 32);
            *(bf16x8*)&Ks[sr][sc] = k0v;
            *(bf16x8*)&Ks[sr][sc + 32] = k1v;
            bf16x8 v0v = *(const bf16x8*)(vg + off);
            bf16x8 v1v = *(const bf16x8*)(vg + off + 32);
#pragma unroll
            for (int j = 0; j < 8; ++j) {
                Vt[sc + j][sr] = v0v[j];
                Vt[sc + 32 + j][sr] = v1v[j];
            }
        }
        __syncthreads();

        f32x4 scr[4];
#pragma unroll
        for (int nt = 0; nt < 4; ++nt) {
            bf16x8 bk0 = *(const bf16x8*)&Ks[nt * 16 + frow][quad * 8];
            bf16x8 bk1 = *(const bf16x8*)&Ks[nt * 16 + frow][32 + quad * 8];
            f32x4 z = 0.0f;
            z = __builtin_amdgcn_mfma_f32_16x16x32_bf16(aq0, bk0, z, 0, 0, 0);
            z = __builtin_amdgcn_mfma_f32_16x16x32_bf16(aq1, bk1, z, 0, 0, 0);
            scr[nt] = z;
        }

        float tmax[4] = {-INFINITY, -INFINITY, -INFINITY, -INFINITY};
#pragma unroll
        for (int nt = 0; nt < 4; ++nt) {
            int kj = k0 + nt * 16 + frow;
            float bias = (kj < LX_) ? mb[kj] : 0.0f;
#pragma unroll
            for (int r = 0; r < 4; ++r) {
                float s = scr[nt][r] * 0.125f + bias;
                if (kj >= LX_ && kj > q0w + quad * 4 + r) s = -INFINITY;
                scr[nt][r] = s;
                tmax[r] = fmaxf(tmax[r], s);
            }
        }
#pragma unroll
        for (int off = 1; off < 16; off <<= 1)
#pragma unroll
            for (int r = 0; r < 4; ++r)
                tmax[r] = fmaxf(tmax[r], __shfl_xor(tmax[r], off, 64));

        float alpha[4], rsum[4];
#pragma unroll
        for (int r = 0; r < 4; ++r) {
            float nm = fmaxf(mrow[r], tmax[r]);
            alpha[r] = (nm == -INFINITY) ? 1.0f : __expf(mrow[r] - nm);
            mrow[r] = nm;
            rsum[r] = 0.0f;
        }
#pragma unroll
        for (int nt = 0; nt < 4; ++nt) {
#pragma unroll
            for (int r = 0; r < 4; ++r) {
                float s = scr[nt][r];
                float p = (s == -INFINITY) ? 0.0f : __expf(s - mrow[r]);
                rsum[r] += p;
                Ps[wave][quad * 4 + r][nt * 16 + frow] = (__bf16)p;
            }
        }
#pragma unroll
        for (int off = 1; off < 16; off <<= 1)
#pragma unroll
            for (int r = 0; r < 4; ++r)
                rsum[r] += __shfl_xor(rsum[r], off, 64);
#pragma unroll
        for (int r = 0; r < 4; ++r)
            lrow[r] = lrow[r] * alpha[r] + rsum[r];
#pragma unroll
        for (int dt = 0; dt < 4; ++dt)
#pragma unroll
            for (int r = 0; r < 4; ++r)
                o[dt][r] *= alpha[r];

        bf16x8 ap0 = *(const bf16x8*)&Ps[wave][frow][quad * 8];
        bf16x8 ap1 = *(const bf16x8*)&Ps[wave][frow][32 + quad * 8];
#pragma unroll
        for (int dt = 0; dt < 4; ++dt) {
            bf16x8 bv0 = *(const bf16x8*)&Vt[dt * 16 + frow][quad * 8];
            bf16x8 bv1 = *(const bf16x8*)&Vt[dt * 16 + frow][32 + quad * 8];
            o[dt] = __builtin_amdgcn_mfma_f32_16x16x32_bf16(ap0, bv0, o[dt], 0, 0, 0);
            o[dt] = __builtin_amdgcn_mfma_f32_16x16x32_bf16(ap1, bv1, o[dt], 0, 0, 0);
        }
        __syncthreads();
    }

#pragma unroll
    for (int r = 0; r < 4; ++r) {
        float inv = (lrow[r] > 0.0f) ? 1.0f / lrow[r] : 0.0f;
        int qg = q0w + quad * 4 + r;
        size_t ob = ((size_t)b * S_ + qg) * D_ + h * HD_;
#pragma unroll
        for (int dt = 0; dt < 4; ++dt)
            ctx[ob + dt * 16 + frow] = (__bf16)(o[dt][r] * inv);
    }
}

// ---------------- fused residual add + LayerNorm (bf16 stream) --------------
__global__ __launch_bounds__(256) void add_ln_kernel(
        __bf16* __restrict__ xs_bf, const __bf16* __restrict__ o,
        const float* __restrict__ g, const float* __restrict__ bb) {
    long row = blockIdx.x;
    __bf16* xr = xs_bf + row * D_;
    const __bf16* orr = o + row * D_;
    int tid = threadIdx.x;
    bf16x4 a4 = *(const bf16x4*)&xr[tid * 4];
    bf16x4 b4v = *(const bf16x4*)&orr[tid * 4];
    float vv[4];
#pragma unroll
    for (int j = 0; j < 4; ++j) vv[j] = (float)a4[j] + (float)b4v[j];
    float s = vv[0] + vv[1] + vv[2] + vv[3];
    __shared__ float red[4];
    __shared__ float stat;
#pragma unroll
    for (int off = 32; off; off >>= 1) s += __shfl_down(s, off, 64);
    if ((tid & 63) == 0) red[tid >> 6] = s;
    __syncthreads();
    if (tid == 0) stat = (red[0] + red[1] + red[2] + red[3]) * (1.0f / 1024.0f);
    __syncthreads();
    float mean = stat;
    float d[4];
    float s2 = 0.0f;
#pragma unroll
    for (int j = 0; j < 4; ++j) { d[j] = vv[j] - mean; s2 += d[j] * d[j]; }
    __syncthreads();
#pragma unroll
    for (int off = 32; off; off >>= 1) s2 += __shfl_down(s2, off, 64);
    if ((tid & 63) == 0) red[tid >> 6] = s2;
    __syncthreads();
    if (tid == 0) stat = (red[0] + red[1] + red[2] + red[3]) * (1.0f / 1024.0f);
    __syncthreads();
    float inv = 1.0f / sqrtf(stat + 1e-5f);
    float4 gg = *(const float4*)&g[tid * 4];
    float4 bv = *(const float4*)&bb[tid * 4];
    float g4[4] = {gg.x, gg.y, gg.z, gg.w};
    float b4[4] = {bv.x, bv.y, bv.z, bv.w};
    bf16x4 ob;
#pragma unroll
    for (int j = 0; j < 4; ++j) ob[j] = (__bf16)(d[j] * inv * g4[j] + b4[j]);
    *(bf16x4*)&xr[tid * 4] = ob;
}

// ---------------- head: (8,1024) @ W_ham^T + b_ham -> (8,144) ----------------
__global__ __launch_bounds__(256) void head_kernel(
        const __bf16* __restrict__ tgt_bf, const float* __restrict__ W_ham,
        const float* __restrict__ b_ham, float* __restrict__ out) {
    int b = blockIdx.x;
    int tid = threadIdx.x;
    __shared__ float xr[D_];
    const __bf16* row = tgt_bf + ((long)b * S_ + (S_ - 1)) * D_;
    for (int i = tid; i < D_; i += 256) xr[i] = (float)row[i];
    __syncthreads();
    for (int n = tid; n < HAM_; n += 256) {
        float acc = b_ham[n];
        const float* wr = W_ham + (long)n * D_;
        for (int kk = 0; kk < D_; ++kk) acc += xr[kk] * wr[kk];
        out[b * HAM_ + n] = acc;
    }
}

// ---------------- loss: mean((head_out - (y - w_last))^2) --------------------
__global__ __launch_bounds__(256) void loss_kernel(
        const float* __restrict__ head_out, const float* __restrict__ y,
        const float* __restrict__ w, float* __restrict__ out) {
    int tid = threadIdx.x;
    float acc = 0.0f;
    for (int i = tid; i < B_ * HAM_; i += 256) {
        int b = i / HAM_, r = i % HAM_;
        float w_last = w[((long)b * 16 + 15) * HAM_ + r];
        float resid = y[i] - w_last;
        float dd = head_out[i] - resid;
        acc += dd * dd;
    }
    __shared__ float red[4];
#pragma unroll
    for (int off = 32; off; off >>= 1) acc += __shfl_down(acc, off, 64);
    if ((tid & 63) == 0) red[tid >> 6] = acc;
    __syncthreads();
    if (tid == 0)
        out[0] = (red[0] + red[1] + red[2] + red[3]) * (1.0f / (B_ * HAM_));
}

// ---------------------------------------------------------------------------
extern "C" void kernel_launch(void* const* d_in, const int* in_sizes, int n_in,
                              void* d_out, int out_size, void* d_ws, size_t ws_size,
                              hipStream_t stream) {
    const float* x      = (const float*)d_in[0];
    const float* w      = (const float*)d_in[1];
    const float* y      = (const float*)d_in[2];
    const float* W_nail = (const float*)d_in[3];
    const float* b_nail = (const float*)d_in[4];
    const float* W_cond = (const float*)d_in[5];
    const float* b_cond = (const float*)d_in[6];
    const float* Wqkv   = (const float*)d_in[7];
    const float* bqkv   = (const float*)d_in[8];
    const float* Wo     = (const float*)d_in[9];
    const float* bo     = (const float*)d_in[10];
    const float* ln1_g  = (const float*)d_in[11];
    const float* ln1_b  = (const float*)d_in[12];
    const float* ln2_g  = (const float*)d_in[13];
    const float* ln2_b  = (const float*)d_in[14];
    const float* W1     = (const float*)d_in[15];
    const float* b1     = (const float*)d_in[16];
    const float* W2     = (const float*)d_in[17];
    const float* b2     = (const float*)d_in[18];
    const float* W_ham  = (const float*)d_in[19];
    const float* b_ham  = (const float*)d_in[20];

    float* ws = (float*)d_ws;
    const long SEG = (long)B_ * S_ * D_;            // 7,340,032 floats
    float*  W_nailT = ws;                           // 64512 floats (in old tgt slot)
    __bf16* tmp_bf = (__bf16*)(ws + SEG);           // [SEG, 1.5SEG)
    __bf16* tgt_bf = (__bf16*)(ws + 2 * SEG);       // [2SEG, 2.5SEG)
    __bf16* ctx_bf = (__bf16*)(ws + 2 * SEG + SEG / 2);      // [2.5SEG, 3SEG)
    __bf16* qb     = (__bf16*)(ws + 3 * SEG);                // [3SEG, 3.5SEG)
    __bf16* kb     = (__bf16*)(ws + 3 * SEG + SEG / 2);      // [3.5SEG, 4SEG)
    __bf16* vb     = (__bf16*)(ws + 4 * SEG);                // [4SEG, 4.5SEG)
    __bf16* ffh_bf = (__bf16*)(ws + 2 * SEG + SEG / 2);      // overlays ctx|q|k|v
    __bf16* wbf    = (__bf16*)(ws + 4 * SEG + SEG / 2);      // 12.58M bf16
    int*    xmask    = (int*)(ws + 4 * SEG + SEG / 2 + 6291456);
    float*  head_out = ws + 4 * SEG + SEG / 2 + 6291456 + 4096;

    __bf16* wqkv_bf = wbf;
    __bf16* wo_bf   = wbf + 3145728;
    __bf16* w1_bf   = wbf + 4194304;
    __bf16* w2_bf   = wbf + 8388608;

    const int M = B_ * S_;                          // 7168

    transpose_nail_kernel<<<252, 256, 0, stream>>>(W_nail, W_nailT);
    embed_x_kernel<<<B_ * LX_ / 8, 256, 0, stream>>>(x, W_nailT, b_nail, tgt_bf, xmask);
    embed_w_kernel<<<B_ * NW_, 256, 0, stream>>>(w, W_cond, b_cond, tgt_bf);

    for (int L = 0; L < 4; ++L) {
        const int NQ = 3 * D_ * D_, NO = D_ * D_, N1 = FF_ * D_, N2 = D_ * FF_;
        convert4_kernel<<<12288, 256, 0, stream>>>(
            Wqkv + (size_t)L * NQ, Wo + (size_t)L * NO,
            W1 + (size_t)L * N1, W2 + (size_t)L * N2,
            wqkv_bf, wo_bf, w1_bf, w2_bf);

        gemm_mfma<2><<<dim3(3 * D_ / 128, M / 128), 256, 0, stream>>>(
            tgt_bf, wqkv_bf, bqkv + (size_t)L * 3 * D_,
            nullptr, qb, kb, vb, M, 3 * D_, D_);
        attn_mfma<<<B_ * H_ * (S_ / 64), 256, 0, stream>>>(qb, kb, vb, xmask, ctx_bf);
        gemm_mfma<0><<<dim3(D_ / 128, M / 128), 256, 0, stream>>>(
            ctx_bf, wo_bf, bo + (size_t)L * D_,
            tmp_bf, nullptr, nullptr, nullptr, M, D_, D_);
        add_ln_kernel<<<M, 256, 0, stream>>>(tgt_bf, tmp_bf,
            ln1_g + (size_t)L * D_, ln1_b + (size_t)L * D_);
        gemm_mfma<1><<<dim3(FF_ / 128, M / 128), 256, 0, stream>>>(
            tgt_bf, w1_bf, b1 + (size_t)L * FF_,
            ffh_bf, nullptr, nullptr, nullptr, M, FF_, D_);
        gemm_mfma<0><<<dim3(D_ / 128, M / 128), 256, 0, stream>>>(
            ffh_bf, w2_bf, b2 + (size_t)L * D_,
            tmp_bf, nullptr, nullptr, nullptr, M, D_, FF_);
        add_ln_kernel<<<M, 256, 0, stream>>>(tgt_bf, tmp_bf,
            ln2_g + (size_t)L * D_, ln2_b + (size_t)L * D_);
    }

    head_kernel<<<B_, 256, 0, stream>>>(tgt_bf, W_ham, b_ham, head_out);
    loss_kernel<<<1, 256, 0, stream>>>(head_out, y, w, (float*)d_out);
}